// Round 3
// baseline (1373.032 us; speedup 1.0000x reference)
//
#include <hip/hip_runtime.h>
#include <cstddef>
#include <cstdint>
#include <math.h>

#define B_   1024
#define L_   18
#define E_   300
#define H_   300
#define M_   (B_*L_)     // 18432 rows (b,l)
#define G4_  (4*H_)      // 1200
#define K2E_ (2*E_)      // 600

// k_mm dims: N = 2*1216 = 2432 (gate-interleaved + pad per dir); K pad 608
#define NPAD 2432
#define KPAD 640          // Wcat row stride (bf16 elems); only k<608 read
#define XGS  1216         // xg row stride (fp32), cols = 4*u+g interleaved

// workspace layout (float offsets)
#define OFF_XGF  ((size_t)0)                          // 18432*1216
#define OFF_XGB  (OFF_XGF + (size_t)M_*XGS)           // 22,413,312
#define OFF_HCAT (OFF_XGB + (size_t)M_*XGS)           // 44,826,624 (bf16 18432x608)
#define OFF_AG   (OFF_HCAT + (size_t)M_*608/2)        // 50,429,952
#define OFF_WBT  (OFF_AG  + (size_t)B_*E_)            // 50,737,152
#define OFF_WFF  (OFF_WBT + 90000)                    // 50,827,152 (bf16 1216x320 frag)
#define OFF_WFB  (OFF_WFF + 194560)                   // 51,021,712
#define OFF_WAT  (OFF_WFB + 194560)                   // 51,216,272 (bf16 19x19x512 frag)
#define OFF_WCAT (OFF_WAT + 92416)                    // 51,308,688 (bf16 2432x640)
// end 52,086,928 floats = 208.3 MB

#define VOFF ((size_t)M_*H_)  // v_g offset in d_out

typedef short bf16x8 __attribute__((ext_vector_type(8)));
typedef float f32x4  __attribute__((ext_vector_type(4)));

__device__ __forceinline__ short f2bf(float f) {
    union { float f; uint32_t u; } c; c.f = f;
    uint32_t u = c.u + 0x7fffu + ((c.u >> 16) & 1u);   // RNE
    return (short)(u >> 16);
}

// ---------------------------------------------------------------------------
// WbT[k][o] = Wb[o*300 + k]
// ---------------------------------------------------------------------------
__global__ void k_prep(const float* __restrict__ Wb, float* __restrict__ WbT)
{
    int idx = blockIdx.x * 256 + threadIdx.x;
    if (idx < 90000) {
        int o = idx % 300;
        int k = idx / 300;
        WbT[idx] = Wb[o * 300 + k];
    }
}

// ---------------------------------------------------------------------------
// Wcat[n'][k] bf16, gate-interleaved rows: n'<1216 fwd (n'=4u+g -> Wih_f[g*300+u]);
// n' in [1216,2432) bwd. Zeros at pads (n' row >= 1200 within dir, k >= 600).
// ---------------------------------------------------------------------------
__global__ __launch_bounds__(256) void k_prep_w(const float* __restrict__ Wih_f,
                                                const float* __restrict__ Wih_b,
                                                short* __restrict__ Wcat)
{
    int idx = blockIdx.x * 256 + threadIdx.x;   // < NPAD*KPAD
    int n = idx / KPAD;
    int k = idx - n * KPAD;
    int fwd = (n < 1216);
    int nn = fwd ? n : n - 1216;
    float v = 0.f;
    if (k < K2E_ && nn < G4_) {
        int u = nn >> 2, g = nn & 3;
        const float* W = fwd ? Wih_f : Wih_b;
        v = W[(size_t)(g * 300 + u) * K2E_ + k];
    }
    Wcat[idx] = f2bf(v);
}

// ---------------------------------------------------------------------------
// Whh fragment-direct pack: WF[d][(nt*10+kt)*512 + lane*8 + j] =
//   bf16(Whh_d[(g*300+u)*300 + k]),  n = nt*16+(lane&15) = 4u+g,
//   k = kt*32 + (lane>>4)*8 + j; zero pads (n>=1200 or k>=300).
// ---------------------------------------------------------------------------
__global__ __launch_bounds__(256) void k_prep_whh(const float* __restrict__ Whh_f,
                                                  const float* __restrict__ Whh_b,
                                                  short* __restrict__ WFf,
                                                  short* __restrict__ WFb)
{
    int idx = blockIdx.x * 256 + threadIdx.x;   // < 389120
    if (idx >= 389120) return;
    int d = blockIdx.y;
    int chunk = idx >> 9;           // nt*10+kt
    int rem   = idx & 511;
    int lane  = rem >> 3;
    int j     = rem & 7;
    int nt = chunk / 10, kt = chunk - nt * 10;
    int n = nt * 16 + (lane & 15);
    int k = kt * 32 + (lane >> 4) * 8 + j;
    float v = 0.f;
    if (n < G4_ && k < H_) {
        int u = n >> 2, g = n & 3;
        const float* W = d ? Whh_b : Whh_f;
        v = W[(size_t)(g * 300 + u) * H_ + k];
    }
    (d ? WFb : WFf)[idx] = f2bf(v);
}

// ---------------------------------------------------------------------------
// Wa fragment-direct pack for k_out: N=304 (19 nt), K=608 (19 kt).
// k' mapping: k'<300 -> k'; 304<=k'<604 -> k'-4 (bwd half); else zero.
// ---------------------------------------------------------------------------
__global__ __launch_bounds__(256) void k_prep_wa(const float* __restrict__ Wa,
                                                 short* __restrict__ WAT)
{
    int idx = blockIdx.x * 256 + threadIdx.x;   // < 184832
    if (idx >= 184832) return;
    int chunk = idx >> 9;           // nt*19+kt
    int rem   = idx & 511;
    int lane  = rem >> 3;
    int j     = rem & 7;
    int nt = chunk / 19, kt = chunk - nt * 19;
    int o  = nt * 16 + (lane & 15);
    int kp = kt * 32 + (lane >> 4) * 8 + j;
    float v = 0.f;
    if (o < H_) {
        int k = -1;
        if (kp < 300)                  k = kp;
        else if (kp >= 304 && kp < 604) k = kp - 4;
        if (k >= 0) v = Wa[(size_t)o * K2E_ + k];
    }
    WAT[idx] = f2bf(v);
}

// ---------------------------------------------------------------------------
// zero hcat pad columns (300..303, 604..607) every call
// ---------------------------------------------------------------------------
__global__ void k_zero(short* __restrict__ hcat)
{
    int r = blockIdx.x * 256 + threadIdx.x;
    if (r < M_) {
        *(uint64_t*)&hcat[(size_t)r * 608 + 300] = 0ull;
        *(uint64_t*)&hcat[(size_t)r * 608 + 604] = 0ull;
    }
}

// ---------------------------------------------------------------------------
// a_g[b][e] = mean_l sem_table[sememes[b][l]][e]
// ---------------------------------------------------------------------------
__global__ __launch_bounds__(256) void k_ag(const int* __restrict__ sem,
                                            const float* __restrict__ sem_table,
                                            float* __restrict__ ag)
{
    int b = blockIdx.x;
    __shared__ int sm[L_];
    if (threadIdx.x < L_) sm[threadIdx.x] = sem[b * L_ + threadIdx.x];
    __syncthreads();
    for (int e = threadIdx.x; e < E_; e += 256) {
        float s = 0.f;
        #pragma unroll
        for (int l = 0; l < L_; ++l) s += sem_table[sm[l] * E_ + e];
        ag[(size_t)b * E_ + e] = s * (1.0f / (float)L_);
    }
}

// ---------------------------------------------------------------------------
// v_g = relu(a_g @ Wb^T + bb) -> d_out[VOFF + ...]
// ---------------------------------------------------------------------------
__global__ __launch_bounds__(256) void k_vg(const float* __restrict__ ag,
                                            const float* __restrict__ WbT,
                                            const float* __restrict__ bbv,
                                            float* __restrict__ out)
{
    int b0 = blockIdx.x * 16;
    __shared__ __align__(16) float ag_s[16 * E_];
    for (int idx = threadIdx.x; idx < 16 * E_; idx += 256)
        ag_s[idx] = ag[(size_t)b0 * E_ + idx];
    __syncthreads();
    for (int o = threadIdx.x; o < E_; o += 256) {
        float acc[16];
        #pragma unroll
        for (int i = 0; i < 16; ++i) acc[i] = 0.f;
        for (int k = 0; k < E_; ++k) {
            float w = WbT[k * E_ + o];
            #pragma unroll
            for (int i = 0; i < 16; ++i)
                acc[i] = fmaf(w, ag_s[i * E_ + k], acc[i]);
        }
        float bias = bbv[o];
        #pragma unroll
        for (int i = 0; i < 16; ++i) {
            float v = acc[i] + bias;
            out[VOFF + (size_t)(b0 + i) * E_ + o] = v > 0.f ? v : 0.f;
        }
    }
}

// ---------------------------------------------------------------------------
// k_mm: xg = x @ Wcat^T + bias   (bf16 MFMA), gate-interleaved output cols.
//   M=18432, N=2432, K=608.  Tiles 128x128x32; 4 waves; C/D layout:
//   col = lane&15, row = (lane>>4)*4 + reg  (verified).
// ---------------------------------------------------------------------------
#define BM 128
#define BN 128
#define BK 32
#define LDT 40

__global__ __launch_bounds__(256) void k_mm(const int* __restrict__ word,
                                            const int* __restrict__ sem,
                                            const float* __restrict__ word_table,
                                            const float* __restrict__ sem_table,
                                            const short* __restrict__ Wcat,
                                            const float* __restrict__ bih_f,
                                            const float* __restrict__ bhh_f,
                                            const float* __restrict__ bih_b,
                                            const float* __restrict__ bhh_b,
                                            float* __restrict__ xgf,
                                            float* __restrict__ xgb)
{
    __shared__ __align__(16) short As[BM * LDT];
    __shared__ __align__(16) short Bs[BN * LDT];
    __shared__ int semL[BM];
    __shared__ int wofL[BM];

    const int m0 = blockIdx.x * BM;
    const int n0 = blockIdx.y * BN;
    const int tid = threadIdx.x;

    if (tid < BM) {
        int m = m0 + tid;
        semL[tid] = sem[m];
        wofL[tid] = word[m / L_] * E_;
    }
    __syncthreads();

    f32x4 acc[4][4];
    #pragma unroll
    for (int i = 0; i < 4; ++i)
        #pragma unroll
        for (int j = 0; j < 4; ++j)
            acc[i][j] = (f32x4){0.f, 0.f, 0.f, 0.f};

    const int wv   = tid >> 6;
    const int lane = tid & 63;
    const int wm   = (wv >> 1) * 64;
    const int wn   = (wv & 1) * 64;
    const int lm   = lane & 15;
    const int quad = lane >> 4;

    const int r  = tid >> 1;
    const int kh = (tid & 1) * 16;
    const int sv  = semL[r];
    const int wof = wofL[r];

    for (int k0 = 0; k0 < 608; k0 += BK) {
        {
            const int kbase = k0 + kh;
            #pragma unroll
            for (int q = 0; q < 4; ++q) {
                int k = kbase + q * 4;
                float4 v;
                if (k < E_)
                    v = (sv == 0) ? *(const float4*)&sem_table[k]
                                  : *(const float4*)&word_table[wof + k];
                else if (k < K2E_)
                    v = *(const float4*)&sem_table[sv * E_ + (k - E_)];
                else
                    v = make_float4(0.f, 0.f, 0.f, 0.f);
                short4 s4;
                s4.x = f2bf(v.x); s4.y = f2bf(v.y);
                s4.z = f2bf(v.z); s4.w = f2bf(v.w);
                *(short4*)&As[r * LDT + kh + q * 4] = s4;
            }
        }
        {
            const short* src = Wcat + (size_t)(n0 + r) * KPAD + k0 + kh;
            *(int4*)&Bs[r * LDT + kh + 0] = *(const int4*)&src[0];
            *(int4*)&Bs[r * LDT + kh + 8] = *(const int4*)&src[8];
        }
        __syncthreads();

        bf16x8 af[4], bfr[4];
        #pragma unroll
        for (int i = 0; i < 4; ++i)
            af[i] = *(const bf16x8*)&As[(wm + 16 * i + lm) * LDT + quad * 8];
        #pragma unroll
        for (int j = 0; j < 4; ++j)
            bfr[j] = *(const bf16x8*)&Bs[(wn + 16 * j + lm) * LDT + quad * 8];
        #pragma unroll
        for (int i = 0; i < 4; ++i)
            #pragma unroll
            for (int j = 0; j < 4; ++j)
                acc[i][j] = __builtin_amdgcn_mfma_f32_16x16x32_bf16(
                    af[i], bfr[j], acc[i][j], 0, 0, 0);
        __syncthreads();
    }

    #pragma unroll
    for (int j = 0; j < 4; ++j) {
        int n = n0 + wn + 16 * j + lm;
        float* dst; int col;
        const float *bi, *bh;
        if (n < 1216) { dst = xgf; col = n;        bi = bih_f; bh = bhh_f; }
        else          { dst = xgb; col = n - 1216; bi = bih_b; bh = bhh_b; }
        float bias = 0.f;
        if (col < G4_) {
            int u = col >> 2, g = col & 3;
            bias = bi[g * 300 + u] + bh[g * 300 + u];
        }
        #pragma unroll
        for (int i = 0; i < 4; ++i) {
            int mb = m0 + wm + 16 * i + quad * 4;
            #pragma unroll
            for (int reg = 0; reg < 4; ++reg)
                dst[(size_t)(mb + reg) * XGS + col] = acc[i][j][reg] + bias;
        }
    }
}

// ---------------------------------------------------------------------------
// k_rec: full 18-step bidirectional LSTM recurrence in ONE launch.
// 128 blocks: (64 batch-groups of 16) x (2 directions). No inter-block deps.
// Per step: gates[16x1216] = h_prev[16x300]@Whh^T via MFMA (B-frags direct
// from L2-resident fragment-packed WF), split in two N-halves to bound LDS;
// then fused elementwise (c in regs) writing h to LDS (bf16) + hcat global.
// ---------------------------------------------------------------------------
__global__ __launch_bounds__(256) void k_rec(const float* __restrict__ xgf,
                                             const float* __restrict__ xgb,
                                             const short* __restrict__ WFf,
                                             const short* __restrict__ WFb,
                                             short* __restrict__ hcat)
{
    const int d = blockIdx.y;
    const float* xg = d ? xgb : xgf;
    const short* WF = d ? WFb : WFf;
    short* hc = hcat + (d ? 304 : 0);
    const int b0 = blockIdx.x * 16;
    const int tid = threadIdx.x;
    const int lane = tid & 63;
    const int wv = tid >> 6;
    const int lm = lane & 15;
    const int quad = lane >> 4;

    __shared__ __align__(16) short h_s[16][328];   // bf16 h_prev, pad-zeroed
    __shared__ __align__(16) float gates[16][620]; // one N-half (608) + pad

    for (int idx = tid; idx < 16 * 328; idx += 256)
        ((short*)h_s)[idx] = 0;
    float c[20];
    #pragma unroll
    for (int i = 0; i < 20; ++i) c[i] = 0.f;
    __syncthreads();

    for (int s = 0; s < L_; ++s) {
        const int t = d ? (L_ - 1 - s) : s;

        // snapshot h_prev into A-fragment registers (reused by both halves)
        bf16x8 a[10];
        if (s > 0) {
            #pragma unroll
            for (int kt = 0; kt < 10; ++kt)
                a[kt] = *(const bf16x8*)&h_s[lm][kt * 32 + quad * 8];
        }

        #pragma unroll
        for (int h = 0; h < 2; ++h) {
            // ---- phase A: GEMM for this N-half (cols h*608 .. h*608+607) ----
            if (s > 0) {
                #pragma unroll
                for (int q = 0; q < 10; ++q) {
                    int ntp = wv + 4 * q;          // tile within half
                    if (ntp < 38) {
                        int nt = h * 38 + ntp;
                        const short* wp = WF + (size_t)nt * 10 * 512 + lane * 8;
                        f32x4 acc = (f32x4){0.f, 0.f, 0.f, 0.f};
                        #pragma unroll
                        for (int kt = 0; kt < 10; ++kt)
                            acc = __builtin_amdgcn_mfma_f32_16x16x32_bf16(
                                a[kt], *(const bf16x8*)(wp + kt * 512), acc, 0, 0, 0);
                        #pragma unroll
                        for (int r = 0; r < 4; ++r)
                            gates[quad * 4 + r][ntp * 16 + lm] = acc[r];
                    }
                }
            }
            __syncthreads();

            // ---- phase B: elementwise LSTM cell for units of this half ----
            #pragma unroll
            for (int ii = 0; ii < 10; ++ii) {
                int j = ii * 256 + tid;
                if (j < 2432) {                    // 16 m * 152 u'
                    int m  = j / 152;
                    int up = j - m * 152;
                    int u  = h * 152 + up;
                    if (u < H_) {
                        float4 xv = *(const float4*)&xg[((size_t)(b0 + m) * L_ + t) * XGS + 4 * u];
                        float gi = xv.x, gf = xv.y, gg = xv.z, go = xv.w;
                        if (s > 0) {
                            float4 gv = *(const float4*)&gates[m][4 * up];
                            gi += gv.x; gf += gv.y; gg += gv.z; go += gv.w;
                        }
                        float iv = 1.f / (1.f + __expf(-gi));
                        float fv = 1.f / (1.f + __expf(-gf));
                        float tg = 1.f - 2.f / (__expf(2.f * gg) + 1.f);
                        float ov = 1.f / (1.f + __expf(-go));
                        float cc = c[h * 10 + ii];
                        cc = fmaf(fv, cc, iv * tg);
                        c[h * 10 + ii] = cc;
                        float th = 1.f - 2.f / (__expf(2.f * cc) + 1.f);
                        short hb16 = f2bf(ov * th);
                        h_s[m][u] = hb16;
                        hc[((size_t)(b0 + m) * L_ + t) * 608 + u] = hb16;
                    }
                }
            }
            __syncthreads();
        }
    }
}

// ---------------------------------------------------------------------------
// k_out: V = relu(hcat @ WAT^T + ba)  bf16 MFMA.  M=18432, N=304(300), K=608.
// A staged in LDS (64x608 bf16); B-frags direct from L2-resident WAT pack.
// ---------------------------------------------------------------------------
__global__ __launch_bounds__(256) void k_out(const short* __restrict__ hcat,
                                             const short* __restrict__ WAT,
                                             const float* __restrict__ ba,
                                             float* __restrict__ out)
{
    const int m0 = blockIdx.x * 64;
    const int tid = threadIdx.x;
    const int lane = tid & 63;
    const int wv = tid >> 6;
    const int lm = lane & 15;
    const int quad = lane >> 4;

    __shared__ __align__(16) short A_s[64][616];

    for (int idx = tid; idx < 4864; idx += 256) {   // 64 rows * 76 chunks
        int r = idx / 76, c8 = idx - r * 76;
        *(int4*)&A_s[r][c8 * 8] = *(const int4*)&hcat[(size_t)(m0 + r) * 608 + c8 * 8];
    }
    __syncthreads();

    f32x4 acc[4][5];
    #pragma unroll
    for (int mt = 0; mt < 4; ++mt)
        #pragma unroll
        for (int q = 0; q < 5; ++q)
            acc[mt][q] = (f32x4){0.f, 0.f, 0.f, 0.f};

    for (int kt = 0; kt < 19; ++kt) {
        bf16x8 af[4];
        #pragma unroll
        for (int mt = 0; mt < 4; ++mt)
            af[mt] = *(const bf16x8*)&A_s[mt * 16 + lm][kt * 32 + quad * 8];
        #pragma unroll
        for (int q = 0; q < 5; ++q) {
            int nt = wv + 4 * q;
            if (nt < 19) {
                bf16x8 bf = *(const bf16x8*)&WAT[((size_t)(nt * 19 + kt) * 64 + lane) * 8];
                #pragma unroll
                for (int mt = 0; mt < 4; ++mt)
                    acc[mt][q] = __builtin_amdgcn_mfma_f32_16x16x32_bf16(
                        af[mt], bf, acc[mt][q], 0, 0, 0);
            }
        }
    }

    #pragma unroll
    for (int q = 0; q < 5; ++q) {
        int nt = wv + 4 * q;
        if (nt < 19) {
            int o = nt * 16 + lm;
            if (o < H_) {
                float bias = ba[o];
                #pragma unroll
                for (int mt = 0; mt < 4; ++mt) {
                    #pragma unroll
                    for (int r = 0; r < 4; ++r) {
                        int m = m0 + mt * 16 + quad * 4 + r;
                        float v = acc[mt][q][r] + bias;
                        out[(size_t)m * H_ + o] = v > 0.f ? v : 0.f;
                    }
                }
            }
        }
    }
}

// ---------------------------------------------------------------------------
extern "C" void kernel_launch(void* const* d_in, const int* in_sizes, int n_in,
                              void* d_out, int out_size, void* d_ws, size_t ws_size,
                              hipStream_t stream) {
    const int*   word       = (const int*)  d_in[0];
    const int*   sem        = (const int*)  d_in[1];
    const float* word_table = (const float*)d_in[2];
    const float* sem_table  = (const float*)d_in[3];
    const float* Wih_f      = (const float*)d_in[4];
    const float* Whh_f      = (const float*)d_in[5];
    const float* bih_f      = (const float*)d_in[6];
    const float* bhh_f      = (const float*)d_in[7];
    const float* Wih_b      = (const float*)d_in[8];
    const float* Whh_b      = (const float*)d_in[9];
    const float* bih_b      = (const float*)d_in[10];
    const float* bhh_b      = (const float*)d_in[11];
    const float* Wa         = (const float*)d_in[12];
    const float* ba         = (const float*)d_in[13];
    const float* Wb         = (const float*)d_in[14];
    const float* bbv        = (const float*)d_in[15];

    float* out = (float*)d_out;
    float* ws  = (float*)d_ws;

    float* xgf  = ws + OFF_XGF;
    float* xgb  = ws + OFF_XGB;
    short* hcat = (short*)(ws + OFF_HCAT);
    float* ag   = ws + OFF_AG;
    float* WbT  = ws + OFF_WBT;
    short* WFf  = (short*)(ws + OFF_WFF);
    short* WFb  = (short*)(ws + OFF_WFB);
    short* WAT  = (short*)(ws + OFF_WAT);
    short* Wcat = (short*)(ws + OFF_WCAT);

    // weight re-layouts (every call; inputs restored each launch)
    k_prep<<<dim3(352), dim3(256), 0, stream>>>(Wb, WbT);
    k_prep_w<<<dim3((NPAD * KPAD) / 256), dim3(256), 0, stream>>>(Wih_f, Wih_b, Wcat);
    k_prep_whh<<<dim3(1520, 2), dim3(256), 0, stream>>>(Whh_f, Whh_b, WFf, WFb);
    k_prep_wa<<<dim3(722), dim3(256), 0, stream>>>(Wa, WAT);
    k_zero<<<dim3((M_ + 255) / 256), dim3(256), 0, stream>>>(hcat);

    // v_g branch
    k_ag<<<dim3(B_), dim3(256), 0, stream>>>(sem, sem_table, ag);
    k_vg<<<dim3(B_ / 16), dim3(256), 0, stream>>>(ag, WbT, bbv, out);

    // input GEMM (both dirs, gather fused, gate-interleaved)
    k_mm<<<dim3(M_ / BM, NPAD / BN), dim3(256), 0, stream>>>(
        word, sem, word_table, sem_table, Wcat,
        bih_f, bhh_f, bih_b, bhh_b, xgf, xgb);

    // full recurrence in one launch
    k_rec<<<dim3(64, 2), dim3(256), 0, stream>>>(xgf, xgb, WFf, WFb, hcat);

    // output projection (bf16 MFMA)
    k_out<<<dim3(M_ / 64), dim3(256), 0, stream>>>(hcat, WAT, ba, out);
}

// Round 4
// 776.056 us; speedup vs baseline: 1.7692x; 1.7692x over previous
//
#include <hip/hip_runtime.h>
#include <cstddef>
#include <cstdint>
#include <math.h>

#define B_   1024
#define L_   18
#define E_   300
#define H_   300
#define M_   (B_*L_)     // 18432 rows (b,l)
#define G4_  (4*H_)      // 1200
#define K2E_ (2*E_)      // 600

// k_mm dims: N = 2*1216 = 2432 (gate-interleaved + pad per dir); K pad 608
#define NPAD 2432
#define KPAD 640          // Wcat row stride (bf16 elems); only k<608 read
#define XGS  1216         // xg row stride (fp32), cols = 4*u+g interleaved

// workspace layout (float offsets)
#define OFF_XGF  ((size_t)0)                          // 18432*1216
#define OFF_XGB  (OFF_XGF + (size_t)M_*XGS)           // 22,413,312
#define OFF_HCAT (OFF_XGB + (size_t)M_*XGS)           // 44,826,624 (bf16 18432x608)
#define OFF_AG   (OFF_HCAT + (size_t)M_*608/2)        // 50,429,952
#define OFF_WBT  (OFF_AG  + (size_t)B_*E_)            // 50,737,152
#define OFF_WFF  (OFF_WBT + 90000)                    // 50,827,152 (bf16 76x10x512 frag)
#define OFF_WFB  (OFF_WFF + 194560)                   // 51,021,712
#define OFF_WAT  (OFF_WFB + 194560)                   // 51,216,272 (bf16 19x19x512 frag)
#define OFF_WCAT (OFF_WAT + 92416)                    // 51,308,688 (bf16 2432x640)
#define OFF_HP   (OFF_WCAT + 778240)                  // 52,086,928 (bf16 4x1024x320 ping-pong)
#define OFF_C    (OFF_HP + 655360)                    // 52,742,288 (fp32 2x1024x304 cell state)
// end 53,364,880 floats = 213.5 MB

#define HPSTR 327680      // shorts per hprev buffer (1024*320)

#define VOFF ((size_t)M_*H_)  // v_g offset in d_out

typedef short bf16x8 __attribute__((ext_vector_type(8)));
typedef float f32x4  __attribute__((ext_vector_type(4)));

__device__ __forceinline__ short f2bf(float f) {
    union { float f; uint32_t u; } c; c.f = f;
    uint32_t u = c.u + 0x7fffu + ((c.u >> 16) & 1u);   // RNE
    return (short)(u >> 16);
}

// ---------------------------------------------------------------------------
// WbT[k][o] = Wb[o*300 + k]
// ---------------------------------------------------------------------------
__global__ void k_prep(const float* __restrict__ Wb, float* __restrict__ WbT)
{
    int idx = blockIdx.x * 256 + threadIdx.x;
    if (idx < 90000) {
        int o = idx % 300;
        int k = idx / 300;
        WbT[idx] = Wb[o * 300 + k];
    }
}

// ---------------------------------------------------------------------------
// Wcat[n'][k] bf16, gate-interleaved rows: n'<1216 fwd (n'=4u+g -> Wih_f[g*300+u]);
// n' in [1216,2432) bwd. Zeros at pads.
// ---------------------------------------------------------------------------
__global__ __launch_bounds__(256) void k_prep_w(const float* __restrict__ Wih_f,
                                                const float* __restrict__ Wih_b,
                                                short* __restrict__ Wcat)
{
    int idx = blockIdx.x * 256 + threadIdx.x;   // < NPAD*KPAD
    int n = idx / KPAD;
    int k = idx - n * KPAD;
    int fwd = (n < 1216);
    int nn = fwd ? n : n - 1216;
    float v = 0.f;
    if (k < K2E_ && nn < G4_) {
        int u = nn >> 2, g = nn & 3;
        const float* W = fwd ? Wih_f : Wih_b;
        v = W[(size_t)(g * 300 + u) * K2E_ + k];
    }
    Wcat[idx] = f2bf(v);
}

// ---------------------------------------------------------------------------
// Whh fragment-direct pack: WF[d][(nt*10+kt)*512 + lane*8 + j] =
//   bf16(Whh_d[(g*300+u)*300 + k]),  n = nt*16+(lane&15) = 4u+g,
//   k = kt*32 + (lane>>4)*8 + j; zero pads (n>=1200 or k>=300).
// ---------------------------------------------------------------------------
__global__ __launch_bounds__(256) void k_prep_whh(const float* __restrict__ Whh_f,
                                                  const float* __restrict__ Whh_b,
                                                  short* __restrict__ WFf,
                                                  short* __restrict__ WFb)
{
    int idx = blockIdx.x * 256 + threadIdx.x;   // < 389120
    if (idx >= 389120) return;
    int d = blockIdx.y;
    int chunk = idx >> 9;           // nt*10+kt
    int rem   = idx & 511;
    int lane  = rem >> 3;
    int j     = rem & 7;
    int nt = chunk / 10, kt = chunk - nt * 10;
    int n = nt * 16 + (lane & 15);
    int k = kt * 32 + (lane >> 4) * 8 + j;
    float v = 0.f;
    if (n < G4_ && k < H_) {
        int u = n >> 2, g = n & 3;
        const float* W = d ? Whh_b : Whh_f;
        v = W[(size_t)(g * 300 + u) * H_ + k];
    }
    (d ? WFb : WFf)[idx] = f2bf(v);
}

// ---------------------------------------------------------------------------
// Wa fragment-direct pack for k_out: N=304 (19 nt), K=608 (19 kt).
// ---------------------------------------------------------------------------
__global__ __launch_bounds__(256) void k_prep_wa(const float* __restrict__ Wa,
                                                 short* __restrict__ WAT)
{
    int idx = blockIdx.x * 256 + threadIdx.x;   // < 184832
    if (idx >= 184832) return;
    int chunk = idx >> 9;           // nt*19+kt
    int rem   = idx & 511;
    int lane  = rem >> 3;
    int j     = rem & 7;
    int nt = chunk / 19, kt = chunk - nt * 19;
    int o  = nt * 16 + (lane & 15);
    int kp = kt * 32 + (lane >> 4) * 8 + j;
    float v = 0.f;
    if (o < H_) {
        int k = -1;
        if (kp < 300)                   k = kp;
        else if (kp >= 304 && kp < 604) k = kp - 4;
        if (k >= 0) v = Wa[(size_t)o * K2E_ + k];
    }
    WAT[idx] = f2bf(v);
}

// ---------------------------------------------------------------------------
// zero pads every call: hcat cols 300-303/604-607; hprev cols 300-319 (4 bufs)
// ---------------------------------------------------------------------------
__global__ void k_zero(short* __restrict__ hcat, short* __restrict__ hp)
{
    int r = blockIdx.x * 256 + threadIdx.x;
    if (r < M_) {
        *(uint64_t*)&hcat[(size_t)r * 608 + 300] = 0ull;
        *(uint64_t*)&hcat[(size_t)r * 608 + 604] = 0ull;
    }
    if (r < 4096) {
        int buf = r >> 10, row = r & 1023;
        short* p = hp + (size_t)buf * HPSTR + (size_t)row * 320 + 300;
        #pragma unroll
        for (int i = 0; i < 5; ++i) *(uint64_t*)&p[i * 4] = 0ull;
    }
}

// ---------------------------------------------------------------------------
// a_g[b][e] = mean_l sem_table[sememes[b][l]][e]
// ---------------------------------------------------------------------------
__global__ __launch_bounds__(256) void k_ag(const int* __restrict__ sem,
                                            const float* __restrict__ sem_table,
                                            float* __restrict__ ag)
{
    int b = blockIdx.x;
    __shared__ int sm[L_];
    if (threadIdx.x < L_) sm[threadIdx.x] = sem[b * L_ + threadIdx.x];
    __syncthreads();
    for (int e = threadIdx.x; e < E_; e += 256) {
        float s = 0.f;
        #pragma unroll
        for (int l = 0; l < L_; ++l) s += sem_table[sm[l] * E_ + e];
        ag[(size_t)b * E_ + e] = s * (1.0f / (float)L_);
    }
}

// ---------------------------------------------------------------------------
// v_g = relu(a_g @ Wb^T + bb) -> d_out[VOFF + ...]
// ---------------------------------------------------------------------------
__global__ __launch_bounds__(256) void k_vg(const float* __restrict__ ag,
                                            const float* __restrict__ WbT,
                                            const float* __restrict__ bbv,
                                            float* __restrict__ out)
{
    int b0 = blockIdx.x * 16;
    __shared__ __align__(16) float ag_s[16 * E_];
    for (int idx = threadIdx.x; idx < 16 * E_; idx += 256)
        ag_s[idx] = ag[(size_t)b0 * E_ + idx];
    __syncthreads();
    for (int o = threadIdx.x; o < E_; o += 256) {
        float acc[16];
        #pragma unroll
        for (int i = 0; i < 16; ++i) acc[i] = 0.f;
        for (int k = 0; k < E_; ++k) {
            float w = WbT[k * E_ + o];
            #pragma unroll
            for (int i = 0; i < 16; ++i)
                acc[i] = fmaf(w, ag_s[i * E_ + k], acc[i]);
        }
        float bias = bbv[o];
        #pragma unroll
        for (int i = 0; i < 16; ++i) {
            float v = acc[i] + bias;
            out[VOFF + (size_t)(b0 + i) * E_ + o] = v > 0.f ? v : 0.f;
        }
    }
}

// ---------------------------------------------------------------------------
// k_mm: xg = x @ Wcat^T + bias   (bf16 MFMA), gate-interleaved output cols.
// ---------------------------------------------------------------------------
#define BM 128
#define BN 128
#define BK 32
#define LDT 40

__global__ __launch_bounds__(256) void k_mm(const int* __restrict__ word,
                                            const int* __restrict__ sem,
                                            const float* __restrict__ word_table,
                                            const float* __restrict__ sem_table,
                                            const short* __restrict__ Wcat,
                                            const float* __restrict__ bih_f,
                                            const float* __restrict__ bhh_f,
                                            const float* __restrict__ bih_b,
                                            const float* __restrict__ bhh_b,
                                            float* __restrict__ xgf,
                                            float* __restrict__ xgb)
{
    __shared__ __align__(16) short As[BM * LDT];
    __shared__ __align__(16) short Bs[BN * LDT];
    __shared__ int semL[BM];
    __shared__ int wofL[BM];

    const int m0 = blockIdx.x * BM;
    const int n0 = blockIdx.y * BN;
    const int tid = threadIdx.x;

    if (tid < BM) {
        int m = m0 + tid;
        semL[tid] = sem[m];
        wofL[tid] = word[m / L_] * E_;
    }
    __syncthreads();

    f32x4 acc[4][4];
    #pragma unroll
    for (int i = 0; i < 4; ++i)
        #pragma unroll
        for (int j = 0; j < 4; ++j)
            acc[i][j] = (f32x4){0.f, 0.f, 0.f, 0.f};

    const int wv   = tid >> 6;
    const int lane = tid & 63;
    const int wm   = (wv >> 1) * 64;
    const int wn   = (wv & 1) * 64;
    const int lm   = lane & 15;
    const int quad = lane >> 4;

    const int r  = tid >> 1;
    const int kh = (tid & 1) * 16;
    const int sv  = semL[r];
    const int wof = wofL[r];

    for (int k0 = 0; k0 < 608; k0 += BK) {
        {
            const int kbase = k0 + kh;
            #pragma unroll
            for (int q = 0; q < 4; ++q) {
                int k = kbase + q * 4;
                float4 v;
                if (k < E_)
                    v = (sv == 0) ? *(const float4*)&sem_table[k]
                                  : *(const float4*)&word_table[wof + k];
                else if (k < K2E_)
                    v = *(const float4*)&sem_table[sv * E_ + (k - E_)];
                else
                    v = make_float4(0.f, 0.f, 0.f, 0.f);
                short4 s4;
                s4.x = f2bf(v.x); s4.y = f2bf(v.y);
                s4.z = f2bf(v.z); s4.w = f2bf(v.w);
                *(short4*)&As[r * LDT + kh + q * 4] = s4;
            }
        }
        {
            const short* src = Wcat + (size_t)(n0 + r) * KPAD + k0 + kh;
            *(int4*)&Bs[r * LDT + kh + 0] = *(const int4*)&src[0];
            *(int4*)&Bs[r * LDT + kh + 8] = *(const int4*)&src[8];
        }
        __syncthreads();

        bf16x8 af[4], bfr[4];
        #pragma unroll
        for (int i = 0; i < 4; ++i)
            af[i] = *(const bf16x8*)&As[(wm + 16 * i + lm) * LDT + quad * 8];
        #pragma unroll
        for (int j = 0; j < 4; ++j)
            bfr[j] = *(const bf16x8*)&Bs[(wn + 16 * j + lm) * LDT + quad * 8];
        #pragma unroll
        for (int i = 0; i < 4; ++i)
            #pragma unroll
            for (int j = 0; j < 4; ++j)
                acc[i][j] = __builtin_amdgcn_mfma_f32_16x16x32_bf16(
                    af[i], bfr[j], acc[i][j], 0, 0, 0);
        __syncthreads();
    }

    #pragma unroll
    for (int j = 0; j < 4; ++j) {
        int n = n0 + wn + 16 * j + lm;
        float* dst; int col;
        const float *bi, *bh;
        if (n < 1216) { dst = xgf; col = n;        bi = bih_f; bh = bhh_f; }
        else          { dst = xgb; col = n - 1216; bi = bih_b; bh = bhh_b; }
        float bias = 0.f;
        if (col < G4_) {
            int u = col >> 2, g = col & 3;
            bias = bi[g * 300 + u] + bh[g * 300 + u];
        }
        #pragma unroll
        for (int i = 0; i < 4; ++i) {
            int mb = m0 + wm + 16 * i + quad * 4;
            #pragma unroll
            for (int reg = 0; reg < 4; ++reg)
                dst[(size_t)(mb + reg) * XGS + col] = acc[i][j][reg] + bias;
        }
    }
}

// ---------------------------------------------------------------------------
// k_step2: ONE recurrence step, both dirs. Grid (16 mb, 19 nb, 2 d), 256 thr.
// gates[64m x 64col] = h_prev[64x320] @ Whh^T (MFMA, A-frags direct from
// L2-resident hprev ping-pong buffer, B-frags direct from WF pack).
// Epilogue: C tile -> LDS -> fused LSTM cell; h -> hcat (bf16) + hprev.
// ---------------------------------------------------------------------------
__global__ __launch_bounds__(256) void k_step2(const float* __restrict__ xgf,
                                               const float* __restrict__ xgb,
                                               const short* __restrict__ WFf,
                                               const short* __restrict__ WFb,
                                               short* __restrict__ hp,
                                               float* __restrict__ cbuf,
                                               short* __restrict__ hcat,
                                               int s)
{
    const int d  = blockIdx.z;
    const float* xg = d ? xgb : xgf;
    const short* WF = d ? WFb : WFf;
    const int t = d ? (L_ - 1 - s) : s;
    const short* hin = hp + (size_t)(d * 2 + ((s + 1) & 1)) * HPSTR;
    short*      hout = hp + (size_t)(d * 2 + (s & 1)) * HPSTR;
    short* hc = hcat + (d ? 304 : 0);
    float* cp = cbuf + (size_t)d * (1024 * 304);

    const int m0 = blockIdx.x * 64;       // batch rows
    const int nb = blockIdx.y;            // unit group: units nb*16 .. nb*16+15
    const int tid  = threadIdx.x;
    const int lane = tid & 63;
    const int wv   = tid >> 6;
    const int lm   = lane & 15;
    const int quad = lane >> 4;

    __shared__ __align__(16) float Cs[64][68];

    f32x4 acc[4];
    #pragma unroll
    for (int mt = 0; mt < 4; ++mt) acc[mt] = (f32x4){0.f, 0.f, 0.f, 0.f};

    if (s > 0) {
        const short* wp = WF + ((size_t)(nb * 4 + wv) * 10) * 512 + lane * 8;
        #pragma unroll
        for (int kt = 0; kt < 10; ++kt) {
            bf16x8 bf = *(const bf16x8*)(wp + kt * 512);
            #pragma unroll
            for (int mt = 0; mt < 4; ++mt) {
                bf16x8 af = *(const bf16x8*)&hin[(size_t)(m0 + mt * 16 + lm) * 320 + kt * 32 + quad * 8];
                acc[mt] = __builtin_amdgcn_mfma_f32_16x16x32_bf16(af, bf, acc[mt], 0, 0, 0);
            }
        }
    }

    // C tile -> LDS (wave wv owns cols wv*16..+15)
    #pragma unroll
    for (int mt = 0; mt < 4; ++mt)
        #pragma unroll
        for (int r = 0; r < 4; ++r)
            Cs[mt * 16 + quad * 4 + r][wv * 16 + lm] = acc[mt][r];
    __syncthreads();

    // fused LSTM cell: thread -> batch row m = tid>>2, units u0..u0+3
    const int m = tid >> 2;
    const int q = tid & 3;
    const int b = m0 + m;
    const int u0 = nb * 16 + 4 * q;       // global unit base
    if (u0 < H_) {
        float4 xv[4];
        #pragma unroll
        for (int i = 0; i < 4; ++i)
            xv[i] = *(const float4*)&xg[((size_t)b * L_ + t) * XGS + (size_t)4 * (u0 + i)];
        float4 cpv = (s > 0) ? *(const float4*)&cp[(size_t)b * 304 + u0]
                             : make_float4(0.f, 0.f, 0.f, 0.f);
        float cold[4] = {cpv.x, cpv.y, cpv.z, cpv.w};
        float cnew[4];
        short hn[4];
        #pragma unroll
        for (int i = 0; i < 4; ++i) {
            float4 gv = *(const float4*)&Cs[m][16 * q + 4 * i];
            float gi = xv[i].x + gv.x;
            float gf = xv[i].y + gv.y;
            float gg = xv[i].z + gv.z;
            float go = xv[i].w + gv.w;
            float iv = 1.f / (1.f + __expf(-gi));
            float fv = 1.f / (1.f + __expf(-gf));
            float tg = 1.f - 2.f / (__expf(2.f * gg) + 1.f);
            float ov = 1.f / (1.f + __expf(-go));
            float cc = fmaf(fv, cold[i], iv * tg);
            cnew[i] = cc;
            float th = 1.f - 2.f / (__expf(2.f * cc) + 1.f);
            hn[i] = f2bf(ov * th);
        }
        *(float4*)&cp[(size_t)b * 304 + u0] = make_float4(cnew[0], cnew[1], cnew[2], cnew[3]);
        short4 h4 = {hn[0], hn[1], hn[2], hn[3]};
        *(short4*)&hout[(size_t)b * 320 + u0] = h4;
        *(short4*)&hc[((size_t)b * L_ + t) * 608 + u0] = h4;
    }
}

// ---------------------------------------------------------------------------
// k_out: V = relu(hcat @ WAT^T + ba)  bf16 MFMA.  M=18432, N=304(300), K=608.
// ---------------------------------------------------------------------------
__global__ __launch_bounds__(256) void k_out(const short* __restrict__ hcat,
                                             const short* __restrict__ WAT,
                                             const float* __restrict__ ba,
                                             float* __restrict__ out)
{
    const int m0 = blockIdx.x * 64;
    const int tid = threadIdx.x;
    const int lane = tid & 63;
    const int wv = tid >> 6;
    const int lm = lane & 15;
    const int quad = lane >> 4;

    __shared__ __align__(16) short A_s[64][616];

    for (int idx = tid; idx < 4864; idx += 256) {   // 64 rows * 76 chunks
        int r = idx / 76, c8 = idx - r * 76;
        *(int4*)&A_s[r][c8 * 8] = *(const int4*)&hcat[(size_t)(m0 + r) * 608 + c8 * 8];
    }
    __syncthreads();

    f32x4 acc[4][5];
    #pragma unroll
    for (int mt = 0; mt < 4; ++mt)
        #pragma unroll
        for (int q = 0; q < 5; ++q)
            acc[mt][q] = (f32x4){0.f, 0.f, 0.f, 0.f};

    for (int kt = 0; kt < 19; ++kt) {
        bf16x8 af[4];
        #pragma unroll
        for (int mt = 0; mt < 4; ++mt)
            af[mt] = *(const bf16x8*)&A_s[mt * 16 + lm][kt * 32 + quad * 8];
        #pragma unroll
        for (int q = 0; q < 5; ++q) {
            int nt = wv + 4 * q;
            if (nt < 19) {
                bf16x8 bf = *(const bf16x8*)&WAT[((size_t)(nt * 19 + kt) * 64 + lane) * 8];
                #pragma unroll
                for (int mt = 0; mt < 4; ++mt)
                    acc[mt][q] = __builtin_amdgcn_mfma_f32_16x16x32_bf16(
                        af[mt], bf, acc[mt][q], 0, 0, 0);
            }
        }
    }

    #pragma unroll
    for (int q = 0; q < 5; ++q) {
        int nt = wv + 4 * q;
        if (nt < 19) {
            int o = nt * 16 + lm;
            if (o < H_) {
                float bias = ba[o];
                #pragma unroll
                for (int mt = 0; mt < 4; ++mt) {
                    #pragma unroll
                    for (int r = 0; r < 4; ++r) {
                        int m = m0 + mt * 16 + quad * 4 + r;
                        float v = acc[mt][q][r] + bias;
                        out[(size_t)m * H_ + o] = v > 0.f ? v : 0.f;
                    }
                }
            }
        }
    }
}

// ---------------------------------------------------------------------------
extern "C" void kernel_launch(void* const* d_in, const int* in_sizes, int n_in,
                              void* d_out, int out_size, void* d_ws, size_t ws_size,
                              hipStream_t stream) {
    const int*   word       = (const int*)  d_in[0];
    const int*   sem        = (const int*)  d_in[1];
    const float* word_table = (const float*)d_in[2];
    const float* sem_table  = (const float*)d_in[3];
    const float* Wih_f      = (const float*)d_in[4];
    const float* Whh_f      = (const float*)d_in[5];
    const float* bih_f      = (const float*)d_in[6];
    const float* bhh_f      = (const float*)d_in[7];
    const float* Wih_b      = (const float*)d_in[8];
    const float* Whh_b      = (const float*)d_in[9];
    const float* bih_b      = (const float*)d_in[10];
    const float* bhh_b      = (const float*)d_in[11];
    const float* Wa         = (const float*)d_in[12];
    const float* ba         = (const float*)d_in[13];
    const float* Wb         = (const float*)d_in[14];
    const float* bbv        = (const float*)d_in[15];

    float* out = (float*)d_out;
    float* ws  = (float*)d_ws;

    float* xgf  = ws + OFF_XGF;
    float* xgb  = ws + OFF_XGB;
    short* hcat = (short*)(ws + OFF_HCAT);
    float* ag   = ws + OFF_AG;
    float* WbT  = ws + OFF_WBT;
    short* WFf  = (short*)(ws + OFF_WFF);
    short* WFb  = (short*)(ws + OFF_WFB);
    short* WAT  = (short*)(ws + OFF_WAT);
    short* Wcat = (short*)(ws + OFF_WCAT);
    short* hp   = (short*)(ws + OFF_HP);
    float* cbuf = ws + OFF_C;

    // weight re-layouts (every call; inputs restored each launch)
    k_prep<<<dim3(352), dim3(256), 0, stream>>>(Wb, WbT);
    k_prep_w<<<dim3((NPAD * KPAD) / 256), dim3(256), 0, stream>>>(Wih_f, Wih_b, Wcat);
    k_prep_whh<<<dim3(1520, 2), dim3(256), 0, stream>>>(Whh_f, Whh_b, WFf, WFb);
    k_prep_wa<<<dim3(722), dim3(256), 0, stream>>>(Wa, WAT);
    k_zero<<<dim3((M_ + 255) / 256), dim3(256), 0, stream>>>(hcat, hp);

    // v_g branch
    k_ag<<<dim3(B_), dim3(256), 0, stream>>>(sem, sem_table, ag);
    k_vg<<<dim3(B_ / 16), dim3(256), 0, stream>>>(ag, WbT, bbv, out);

    // input GEMM (both dirs, gather fused, gate-interleaved)
    k_mm<<<dim3(M_ / BM, NPAD / BN), dim3(256), 0, stream>>>(
        word, sem, word_table, sem_table, Wcat,
        bih_f, bhh_f, bih_b, bhh_b, xgf, xgb);

    // 18 recurrence steps, wide MFMA step kernel (both dirs per launch)
    for (int s = 0; s < L_; ++s) {
        k_step2<<<dim3(16, 19, 2), dim3(256), 0, stream>>>(
            xgf, xgb, WFf, WFb, hp, cbuf, hcat, s);
    }

    // output projection (bf16 MFMA)
    k_out<<<dim3(M_ / 64), dim3(256), 0, stream>>>(hcat, WAT, ba, out);
}

// Round 5
// 533.236 us; speedup vs baseline: 2.5749x; 1.4554x over previous
//
#include <hip/hip_runtime.h>
#include <cstddef>
#include <cstdint>
#include <math.h>

#define B_   1024
#define L_   18
#define E_   300
#define H_   300
#define M_   (B_*L_)     // 18432 rows (b,l)
#define G4_  (4*H_)      // 1200
#define K2E_ (2*E_)      // 600

#define NPAD 2432        // gate-interleaved cols, both dirs (2*1216)
#define PSTR 2432        // P1/P2 row stride (fp32)
#define M2P  2304        // P2 padded rows (2186 valid)

// workspace layout (float offsets)
#define OFF_P1   ((size_t)0)                         // fp32 1024x2432
#define OFF_P2   (OFF_P1 + (size_t)1024*PSTR)        // fp32 2304x2432 (+bias)
#define OFF_HCAT (OFF_P2 + (size_t)M2P*PSTR)         // bf16 18432x608
#define OFF_AG   (OFF_HCAT + (size_t)M_*608/2)
#define OFF_WBT  (OFF_AG  + (size_t)B_*E_)
#define OFF_WFF  (OFF_WBT + 90000)                   // bf16 76x10x512 B-frag
#define OFF_WFB  (OFF_WFF + 194560)
#define OFF_WAT  (OFF_WFB + 194560)                  // bf16 19x19x512 B-frag
#define OFF_WCP  (OFF_WAT + 92416)                   // bf16 2x2432x320
#define OFF_HP   (OFF_WCP + 778240)                  // bf16 4x(64x10x512) A-frag ping-pong
#define OFF_C    (OFF_HP + 655360)                   // fp32 2x1024x304
// end ~16.6M floats = 66.5 MB

#define HPSTR 327680      // shorts per hprev buffer (64rt x 10kt x 512)

#define VOFF ((size_t)M_*H_)  // v_g offset in d_out

typedef short bf16x8 __attribute__((ext_vector_type(8)));
typedef float f32x4  __attribute__((ext_vector_type(4)));

__device__ __forceinline__ short f2bf(float f) {
    union { float f; uint32_t u; } c; c.f = f;
    uint32_t u = c.u + 0x7fffu + ((c.u >> 16) & 1u);   // RNE
    return (short)(u >> 16);
}

// ---------------------------------------------------------------------------
// WbT[k][o] = Wb[o*300 + k]
// ---------------------------------------------------------------------------
__global__ void k_prep(const float* __restrict__ Wb, float* __restrict__ WbT)
{
    int idx = blockIdx.x * 256 + threadIdx.x;
    if (idx < 90000) {
        int o = idx % 300;
        int k = idx / 300;
        WbT[idx] = Wb[o * 300 + k];
    }
}

// ---------------------------------------------------------------------------
// WcatP[p][n'][kp] bf16: p=0 -> Wih[:, kp] (first half), p=1 -> Wih[:, 300+kp].
// n' gate-interleaved: n'<1216 fwd (n'=4u+g -> row g*300+u), else bwd.
// Zero pads (kp>=300, unit>=300).
// ---------------------------------------------------------------------------
__global__ __launch_bounds__(256) void k_prep_wcp(const float* __restrict__ Wih_f,
                                                  const float* __restrict__ Wih_b,
                                                  short* __restrict__ WcatP)
{
    int idx = blockIdx.x * 256 + threadIdx.x;   // < 2*2432*320
    if (idx >= 2 * NPAD * 320) return;
    int p = idx / (NPAD * 320);
    int rem = idx - p * (NPAD * 320);
    int n = rem / 320;
    int kp = rem - n * 320;
    int fwd = (n < 1216);
    int nn = fwd ? n : n - 1216;
    float v = 0.f;
    if (kp < 300 && nn < G4_) {
        int u = nn >> 2, g = nn & 3;
        const float* W = fwd ? Wih_f : Wih_b;
        v = W[(size_t)(g * 300 + u) * K2E_ + (p ? 300 + kp : kp)];
    }
    WcatP[idx] = f2bf(v);
}

// ---------------------------------------------------------------------------
// Whh B-fragment pack: WF[d][(nt*10+kt)*512 + lane*8 + j] =
//   bf16(Whh_d[(g*300+u)*300 + k]),  n = nt*16+(lane&15) = 4u+g,
//   k = kt*32 + (lane>>4)*8 + j; zero pads.
// ---------------------------------------------------------------------------
__global__ __launch_bounds__(256) void k_prep_whh(const float* __restrict__ Whh_f,
                                                  const float* __restrict__ Whh_b,
                                                  short* __restrict__ WFf,
                                                  short* __restrict__ WFb)
{
    int idx = blockIdx.x * 256 + threadIdx.x;   // < 389120
    if (idx >= 389120) return;
    int d = blockIdx.y;
    int chunk = idx >> 9;           // nt*10+kt
    int rem   = idx & 511;
    int lane  = rem >> 3;
    int j     = rem & 7;
    int nt = chunk / 10, kt = chunk - nt * 10;
    int n = nt * 16 + (lane & 15);
    int k = kt * 32 + (lane >> 4) * 8 + j;
    float v = 0.f;
    if (n < G4_ && k < H_) {
        int u = n >> 2, g = n & 3;
        const float* W = d ? Whh_b : Whh_f;
        v = W[(size_t)(g * 300 + u) * H_ + k];
    }
    (d ? WFb : WFf)[idx] = f2bf(v);
}

// ---------------------------------------------------------------------------
// Wa B-fragment pack for k_out: N=304 (19 nt), K=608 (19 kt).
// ---------------------------------------------------------------------------
__global__ __launch_bounds__(256) void k_prep_wa(const float* __restrict__ Wa,
                                                 short* __restrict__ WAT)
{
    int idx = blockIdx.x * 256 + threadIdx.x;   // < 184832
    if (idx >= 184832) return;
    int chunk = idx >> 9;           // nt*19+kt
    int rem   = idx & 511;
    int lane  = rem >> 3;
    int j     = rem & 7;
    int nt = chunk / 19, kt = chunk - nt * 19;
    int o  = nt * 16 + (lane & 15);
    int kp = kt * 32 + (lane >> 4) * 8 + j;
    float v = 0.f;
    if (o < H_) {
        int k = -1;
        if (kp < 300)                   k = kp;
        else if (kp >= 304 && kp < 604) k = kp - 4;
        if (k >= 0) v = Wa[(size_t)o * K2E_ + k];
    }
    WAT[idx] = f2bf(v);
}

// ---------------------------------------------------------------------------
// zero: hcat pad cols + entire hp (pads must stay zero; valid parts rewritten)
// ---------------------------------------------------------------------------
__global__ void k_zero(short* __restrict__ hcat, short* __restrict__ hp)
{
    int r = blockIdx.x * 256 + threadIdx.x;     // 18432 threads
    if (r < M_) {
        *(uint64_t*)&hcat[(size_t)r * 608 + 300] = 0ull;
        *(uint64_t*)&hcat[(size_t)r * 608 + 604] = 0ull;
    }
    uint64_t* hp8 = (uint64_t*)hp;              // 4*327680 shorts = 327680 u64
    for (int i = r; i < 327680; i += M_) hp8[i] = 0ull;
}

// ---------------------------------------------------------------------------
// a_g[b][e] = mean_l sem_table[sememes[b][l]][e]
// ---------------------------------------------------------------------------
__global__ __launch_bounds__(256) void k_ag(const int* __restrict__ sem,
                                            const float* __restrict__ sem_table,
                                            float* __restrict__ ag)
{
    int b = blockIdx.x;
    __shared__ int sm[L_];
    if (threadIdx.x < L_) sm[threadIdx.x] = sem[b * L_ + threadIdx.x];
    __syncthreads();
    for (int e = threadIdx.x; e < E_; e += 256) {
        float s = 0.f;
        #pragma unroll
        for (int l = 0; l < L_; ++l) s += sem_table[sm[l] * E_ + e];
        ag[(size_t)b * E_ + e] = s * (1.0f / (float)L_);
    }
}

// ---------------------------------------------------------------------------
// v_g = relu(a_g @ Wb^T + bb) -> d_out[VOFF + ...]
// ---------------------------------------------------------------------------
__global__ __launch_bounds__(256) void k_vg(const float* __restrict__ ag,
                                            const float* __restrict__ WbT,
                                            const float* __restrict__ bbv,
                                            float* __restrict__ out)
{
    int b0 = blockIdx.x * 16;
    __shared__ __align__(16) float ag_s[16 * E_];
    for (int idx = threadIdx.x; idx < 16 * E_; idx += 256)
        ag_s[idx] = ag[(size_t)b0 * E_ + idx];
    __syncthreads();
    for (int o = threadIdx.x; o < E_; o += 256) {
        float acc[16];
        #pragma unroll
        for (int i = 0; i < 16; ++i) acc[i] = 0.f;
        for (int k = 0; k < E_; ++k) {
            float w = WbT[k * E_ + o];
            #pragma unroll
            for (int i = 0; i < 16; ++i)
                acc[i] = fmaf(w, ag_s[i * E_ + k], acc[i]);
        }
        float bias = bbv[o];
        #pragma unroll
        for (int i = 0; i < 16; ++i) {
            float v = acc[i] + bias;
            out[VOFF + (size_t)(b0 + i) * E_ + o] = v > 0.f ? v : 0.f;
        }
    }
}

// ---------------------------------------------------------------------------
// k_p: P1 = w @ Wih1^T  (rows 0..1023, mb 0..7)
//      P2' = sem_table @ Wih2^T + bias  (rows 0..2303, mb 8..25)
// bf16 MFMA, 128x128 tiles, K=320 (300 valid). Grid (26, 19).
// ---------------------------------------------------------------------------
#define LDT 40

__global__ __launch_bounds__(256) void k_p(const int* __restrict__ word,
                                           const float* __restrict__ word_table,
                                           const float* __restrict__ sem_table,
                                           const short* __restrict__ WcatP,
                                           const float* __restrict__ bih_f,
                                           const float* __restrict__ bhh_f,
                                           const float* __restrict__ bih_b,
                                           const float* __restrict__ bhh_b,
                                           float* __restrict__ P1,
                                           float* __restrict__ P2)
{
    __shared__ __align__(16) short As[128 * LDT];
    __shared__ __align__(16) short Bs[128 * LDT];
    __shared__ const float* rowp[128];

    const int mb = blockIdx.x;
    const int p  = (mb >= 8);
    const int m0 = (p ? mb - 8 : mb) * 128;
    const int n0 = blockIdx.y * 128;
    const int tid = threadIdx.x;

    if (tid < 128) {
        int m = m0 + tid;
        rowp[tid] = p ? (m < 2186 ? sem_table + (size_t)m * E_ : (const float*)0)
                      : word_table + (size_t)word[m] * E_;
    }
    __syncthreads();

    f32x4 acc[4][4];
    #pragma unroll
    for (int i = 0; i < 4; ++i)
        #pragma unroll
        for (int j = 0; j < 4; ++j)
            acc[i][j] = (f32x4){0.f, 0.f, 0.f, 0.f};

    const int wv   = tid >> 6;
    const int lane = tid & 63;
    const int wm   = (wv >> 1) * 64;
    const int wn   = (wv & 1) * 64;
    const int lm   = lane & 15;
    const int quad = lane >> 4;

    const int r  = tid >> 1;
    const int kh = (tid & 1) * 16;
    const float* rp = rowp[r];
    const short* bsrc = WcatP + (size_t)p * (NPAD * 320) + (size_t)(n0 + r) * 320;

    for (int k0 = 0; k0 < 320; k0 += 32) {
        {
            const int kbase = k0 + kh;
            #pragma unroll
            for (int q = 0; q < 4; ++q) {
                int k = kbase + q * 4;
                float4 v = (k < E_ && rp) ? *(const float4*)&rp[k]
                                          : make_float4(0.f, 0.f, 0.f, 0.f);
                short4 s4;
                s4.x = f2bf(v.x); s4.y = f2bf(v.y);
                s4.z = f2bf(v.z); s4.w = f2bf(v.w);
                *(short4*)&As[r * LDT + kh + q * 4] = s4;
            }
        }
        {
            const short* src = bsrc + k0 + kh;
            *(int4*)&Bs[r * LDT + kh + 0] = *(const int4*)&src[0];
            *(int4*)&Bs[r * LDT + kh + 8] = *(const int4*)&src[8];
        }
        __syncthreads();

        bf16x8 af[4], bfr[4];
        #pragma unroll
        for (int i = 0; i < 4; ++i)
            af[i] = *(const bf16x8*)&As[(wm + 16 * i + lm) * LDT + quad * 8];
        #pragma unroll
        for (int j = 0; j < 4; ++j)
            bfr[j] = *(const bf16x8*)&Bs[(wn + 16 * j + lm) * LDT + quad * 8];
        #pragma unroll
        for (int i = 0; i < 4; ++i)
            #pragma unroll
            for (int j = 0; j < 4; ++j)
                acc[i][j] = __builtin_amdgcn_mfma_f32_16x16x32_bf16(
                    af[i], bfr[j], acc[i][j], 0, 0, 0);
        __syncthreads();
    }

    float* dst = p ? P2 : P1;
    #pragma unroll
    for (int j = 0; j < 4; ++j) {
        int n = n0 + wn + 16 * j + lm;
        float bias = 0.f;
        if (p) {
            int fwd = (n < 1216);
            int cc = fwd ? n : n - 1216;
            if (cc < G4_) {
                int u = cc >> 2, g = cc & 3;
                bias = fwd ? (bih_f[g * 300 + u] + bhh_f[g * 300 + u])
                           : (bih_b[g * 300 + u] + bhh_b[g * 300 + u]);
            }
        }
        #pragma unroll
        for (int i = 0; i < 4; ++i) {
            int mb2 = m0 + wm + 16 * i + quad * 4;
            #pragma unroll
            for (int reg = 0; reg < 4; ++reg)
                dst[(size_t)(mb2 + reg) * PSTR + n] = acc[i][j][reg] + bias;
        }
    }
}

// ---------------------------------------------------------------------------
// k_step2: ONE recurrence step, both dirs. Grid (16 mb, 19 nb, 2 d), 256 thr.
// gates = h_prev @ Whh^T via MFMA; A-frags contiguous from fragment-layout
// hp ping-pong (L2), B-frags from WF pack (L2). Epilogue: C->LDS->fused cell
// with x-part gathered from P1/P2' rows; h -> hcat(bf16) + hp (frag layout).
// ---------------------------------------------------------------------------
__global__ __launch_bounds__(256) void k_step2(const float* __restrict__ P1,
                                               const float* __restrict__ P2,
                                               const int* __restrict__ sem,
                                               const short* __restrict__ WFf,
                                               const short* __restrict__ WFb,
                                               short* __restrict__ hp,
                                               float* __restrict__ cbuf,
                                               short* __restrict__ hcat,
                                               int s)
{
    const int d  = blockIdx.z;
    const short* WF = d ? WFb : WFf;
    const int t = d ? (L_ - 1 - s) : s;
    const short* hin = hp + (size_t)(d * 2 + ((s + 1) & 1)) * HPSTR;
    short*      hout = hp + (size_t)(d * 2 + (s & 1)) * HPSTR;
    short* hc = hcat + (d ? 304 : 0);
    float* cp = cbuf + (size_t)d * (1024 * 304);

    const int m0 = blockIdx.x * 64;       // batch rows
    const int rt0 = blockIdx.x * 4;       // row-tiles of 16
    const int nb = blockIdx.y;            // units nb*16..+15
    const int tid  = threadIdx.x;
    const int lane = tid & 63;
    const int wv   = tid >> 6;
    const int lm   = lane & 15;
    const int quad = lane >> 4;

    __shared__ __align__(16) float Cs[64][68];

    f32x4 acc[4];
    #pragma unroll
    for (int mt = 0; mt < 4; ++mt) acc[mt] = (f32x4){0.f, 0.f, 0.f, 0.f};

    if (s > 0) {
        const short* wp = WF + ((size_t)(nb * 4 + wv) * 10) * 512 + lane * 8;
        #pragma unroll
        for (int kt = 0; kt < 10; ++kt) {
            bf16x8 bf = *(const bf16x8*)(wp + kt * 512);
            #pragma unroll
            for (int mt = 0; mt < 4; ++mt) {
                bf16x8 af = *(const bf16x8*)&hin[((size_t)(rt0 + mt) * 10 + kt) * 512 + lane * 8];
                acc[mt] = __builtin_amdgcn_mfma_f32_16x16x32_bf16(af, bf, acc[mt], 0, 0, 0);
            }
        }
    }

    // C tile -> LDS (wave wv owns cols wv*16..+15 of the 64-col block)
    #pragma unroll
    for (int mt = 0; mt < 4; ++mt)
        #pragma unroll
        for (int r = 0; r < 4; ++r)
            Cs[mt * 16 + quad * 4 + r][wv * 16 + lm] = acc[mt][r];
    __syncthreads();

    // fused LSTM cell: thread -> batch row m=tid>>2, units u0..u0+3
    const int m = tid >> 2;
    const int q = tid & 3;
    const int b = m0 + m;
    const int u0 = nb * 16 + 4 * q;
    if (u0 < H_) {
        const int svt = sem[b * L_ + t];
        const size_t pcol = (size_t)d * 1216 + 4 * u0;
        const float* p2r = P2 + (size_t)svt * PSTR + pcol;
        const float* p1r = P1 + (size_t)b * PSTR + pcol;
        float4 xv[4];
        #pragma unroll
        for (int i = 0; i < 4; ++i) xv[i] = *(const float4*)&p2r[4 * i];
        if (svt != 0) {
            #pragma unroll
            for (int i = 0; i < 4; ++i) {
                float4 a = *(const float4*)&p1r[4 * i];
                xv[i].x += a.x; xv[i].y += a.y; xv[i].z += a.z; xv[i].w += a.w;
            }
        }
        float4 cpv = (s > 0) ? *(const float4*)&cp[(size_t)b * 304 + u0]
                             : make_float4(0.f, 0.f, 0.f, 0.f);
        float cold[4] = {cpv.x, cpv.y, cpv.z, cpv.w};
        float cnew[4];
        short hn[4];
        #pragma unroll
        for (int i = 0; i < 4; ++i) {
            float4 gv = *(const float4*)&Cs[m][16 * q + 4 * i];
            float gi = xv[i].x + gv.x;
            float gf = xv[i].y + gv.y;
            float gg = xv[i].z + gv.z;
            float go = xv[i].w + gv.w;
            float iv = 1.f / (1.f + __expf(-gi));
            float fv = 1.f / (1.f + __expf(-gf));
            float tg = 1.f - 2.f / (__expf(2.f * gg) + 1.f);
            float ov = 1.f / (1.f + __expf(-go));
            float cc = fmaf(fv, cold[i], iv * tg);
            cnew[i] = cc;
            float th = 1.f - 2.f / (__expf(2.f * cc) + 1.f);
            hn[i] = f2bf(ov * th);
        }
        *(float4*)&cp[(size_t)b * 304 + u0] = make_float4(cnew[0], cnew[1], cnew[2], cnew[3]);
        short4 h4 = {hn[0], hn[1], hn[2], hn[3]};
        // hp fragment layout: rt=b>>4, kt=u0>>5, lane=(b&15)|(((u0>>3)&3)<<4), j0=u0&7
        {
            int rt = b >> 4, ktu = u0 >> 5;
            int fl = (b & 15) | (((u0 >> 3) & 3) << 4);
            *(short4*)&hout[((size_t)(rt * 10 + ktu) * 512) + fl * 8 + (u0 & 7)] = h4;
        }
        *(short4*)&hc[((size_t)b * L_ + t) * 608 + u0] = h4;
    }
}

// ---------------------------------------------------------------------------
// k_out: V = relu(hcat @ WAT^T + ba)  bf16 MFMA.  M=18432, N=304(300), K=608.
// ---------------------------------------------------------------------------
__global__ __launch_bounds__(256) void k_out(const short* __restrict__ hcat,
                                             const short* __restrict__ WAT,
                                             const float* __restrict__ ba,
                                             float* __restrict__ out)
{
    const int m0 = blockIdx.x * 64;
    const int tid = threadIdx.x;
    const int lane = tid & 63;
    const int wv = tid >> 6;
    const int lm = lane & 15;
    const int quad = lane >> 4;

    __shared__ __align__(16) short A_s[64][616];

    for (int idx = tid; idx < 4864; idx += 256) {   // 64 rows * 76 chunks
        int r = idx / 76, c8 = idx - r * 76;
        *(int4*)&A_s[r][c8 * 8] = *(const int4*)&hcat[(size_t)(m0 + r) * 608 + c8 * 8];
    }
    __syncthreads();

    f32x4 acc[4][5];
    #pragma unroll
    for (int mt = 0; mt < 4; ++mt)
        #pragma unroll
        for (int q = 0; q < 5; ++q)
            acc[mt][q] = (f32x4){0.f, 0.f, 0.f, 0.f};

    for (int kt = 0; kt < 19; ++kt) {
        bf16x8 af[4];
        #pragma unroll
        for (int mt = 0; mt < 4; ++mt)
            af[mt] = *(const bf16x8*)&A_s[mt * 16 + lm][kt * 32 + quad * 8];
        #pragma unroll
        for (int q = 0; q < 5; ++q) {
            int nt = wv + 4 * q;
            if (nt < 19) {
                bf16x8 bf = *(const bf16x8*)&WAT[((size_t)(nt * 19 + kt) * 64 + lane) * 8];
                #pragma unroll
                for (int mt = 0; mt < 4; ++mt)
                    acc[mt][q] = __builtin_amdgcn_mfma_f32_16x16x32_bf16(
                        af[mt], bf, acc[mt][q], 0, 0, 0);
            }
        }
    }

    #pragma unroll
    for (int q = 0; q < 5; ++q) {
        int nt = wv + 4 * q;
        if (nt < 19) {
            int o = nt * 16 + lm;
            if (o < H_) {
                float bias = ba[o];
                #pragma unroll
                for (int mt = 0; mt < 4; ++mt) {
                    #pragma unroll
                    for (int r = 0; r < 4; ++r) {
                        int m = m0 + mt * 16 + quad * 4 + r;
                        float v = acc[mt][q][r] + bias;
                        out[(size_t)m * H_ + o] = v > 0.f ? v : 0.f;
                    }
                }
            }
        }
    }
}

// ---------------------------------------------------------------------------
extern "C" void kernel_launch(void* const* d_in, const int* in_sizes, int n_in,
                              void* d_out, int out_size, void* d_ws, size_t ws_size,
                              hipStream_t stream) {
    const int*   word       = (const int*)  d_in[0];
    const int*   sem        = (const int*)  d_in[1];
    const float* word_table = (const float*)d_in[2];
    const float* sem_table  = (const float*)d_in[3];
    const float* Wih_f      = (const float*)d_in[4];
    const float* Whh_f      = (const float*)d_in[5];
    const float* bih_f      = (const float*)d_in[6];
    const float* bhh_f      = (const float*)d_in[7];
    const float* Wih_b      = (const float*)d_in[8];
    const float* Whh_b      = (const float*)d_in[9];
    const float* bih_b      = (const float*)d_in[10];
    const float* bhh_b      = (const float*)d_in[11];
    const float* Wa         = (const float*)d_in[12];
    const float* ba         = (const float*)d_in[13];
    const float* Wb         = (const float*)d_in[14];
    const float* bbv        = (const float*)d_in[15];

    float* out = (float*)d_out;
    float* ws  = (float*)d_ws;

    float* P1    = ws + OFF_P1;
    float* P2    = ws + OFF_P2;
    short* hcat  = (short*)(ws + OFF_HCAT);
    float* ag    = ws + OFF_AG;
    float* WbT   = ws + OFF_WBT;
    short* WFf   = (short*)(ws + OFF_WFF);
    short* WFb   = (short*)(ws + OFF_WFB);
    short* WAT   = (short*)(ws + OFF_WAT);
    short* WcatP = (short*)(ws + OFF_WCP);
    short* hp    = (short*)(ws + OFF_HP);
    float* cbuf  = ws + OFF_C;

    // weight re-layouts (every call; inputs restored each launch)
    k_prep<<<dim3(352), dim3(256), 0, stream>>>(Wb, WbT);
    k_prep_wcp<<<dim3((2 * NPAD * 320 + 255) / 256), dim3(256), 0, stream>>>(
        Wih_f, Wih_b, WcatP);
    k_prep_whh<<<dim3(1520, 2), dim3(256), 0, stream>>>(Whh_f, Whh_b, WFf, WFb);
    k_prep_wa<<<dim3(722), dim3(256), 0, stream>>>(Wa, WAT);
    k_zero<<<dim3((M_ + 255) / 256), dim3(256), 0, stream>>>(hcat, hp);

    // v_g branch
    k_ag<<<dim3(B_), dim3(256), 0, stream>>>(sem, sem_table, ag);
    k_vg<<<dim3(B_ / 16), dim3(256), 0, stream>>>(ag, WbT, bbv, out);

    // factored input GEMMs: P1 (word part) + P2' (sememe part + bias)
    k_p<<<dim3(26, 19), dim3(256), 0, stream>>>(
        word, word_table, sem_table, WcatP,
        bih_f, bhh_f, bih_b, bhh_b, P1, P2);

    // 18 recurrence steps (both dirs per launch); x-part gathered from P1/P2'
    for (int s = 0; s < L_; ++s) {
        k_step2<<<dim3(16, 19, 2), dim3(256), 0, stream>>>(
            P1, P2, sem, WFf, WFb, hp, cbuf, hcat, s);
    }

    // output projection (bf16 MFMA)
    k_out<<<dim3(M_ / 64), dim3(256), 0, stream>>>(hcat, WAT, ba, out);
}

// Round 7
// 532.166 us; speedup vs baseline: 2.5801x; 1.0020x over previous
//
#include <hip/hip_runtime.h>
#include <hip/hip_cooperative_groups.h>
#include <cstddef>
#include <cstdint>
#include <math.h>

namespace cg = cooperative_groups;

#define B_   1024
#define L_   18
#define E_   300
#define H_   300
#define M_   (B_*L_)     // 18432 rows (b,l)
#define G4_  (4*H_)      // 1200
#define K2E_ (2*E_)      // 600

#define NPAD 2432        // gate-interleaved cols, both dirs (2*1216)
#define PSTR 2432        // P1/P2 row stride (fp32)
#define M2P  2304        // P2 padded rows (2186 valid)

// workspace layout (float offsets)
#define OFF_P1   ((size_t)0)                         // fp32 1024x2432
#define OFF_P2   (OFF_P1 + (size_t)1024*PSTR)        // fp32 2304x2432 (+bias)
#define OFF_HCAT (OFF_P2 + (size_t)M2P*PSTR)         // bf16 18432x608
#define OFF_AG   (OFF_HCAT + (size_t)M_*608/2)
#define OFF_WBT  (OFF_AG  + (size_t)B_*E_)
#define OFF_WFF  (OFF_WBT + 90000)                   // bf16 76x10x512 B-frag
#define OFF_WFB  (OFF_WFF + 194560)
#define OFF_WAT  (OFF_WFB + 194560)                  // bf16 19x19x512 B-frag
#define OFF_WCP  (OFF_WAT + 92416)                   // bf16 2x2432x320
#define OFF_HP   (OFF_WCP + 778240)                  // bf16 4x(64x10x512) A-frag ping-pong
#define OFF_C    (OFF_HP + 655360)                   // fp32 2x1024x304 (fallback path only)
// end ~17M floats = 68 MB

#define HPSTR 327680      // shorts per hprev buffer (64rt x 10kt x 512)

#define VOFF ((size_t)M_*H_)  // v_g offset in d_out

typedef short bf16x8 __attribute__((ext_vector_type(8)));
typedef float f32x4  __attribute__((ext_vector_type(4)));

__device__ __forceinline__ short f2bf(float f) {
    union { float f; uint32_t u; } c; c.f = f;
    uint32_t u = c.u + 0x7fffu + ((c.u >> 16) & 1u);   // RNE
    return (short)(u >> 16);
}

// ---------------------------------------------------------------------------
// WbT[k][o] = Wb[o*300 + k]
// ---------------------------------------------------------------------------
__global__ void k_prep(const float* __restrict__ Wb, float* __restrict__ WbT)
{
    int idx = blockIdx.x * 256 + threadIdx.x;
    if (idx < 90000) {
        int o = idx % 300;
        int k = idx / 300;
        WbT[idx] = Wb[o * 300 + k];
    }
}

// ---------------------------------------------------------------------------
// WcatP[p][n'][kp] bf16: p=0 -> Wih[:, kp], p=1 -> Wih[:, 300+kp].
// n' gate-interleaved: n'<1216 fwd (n'=4u+g -> row g*300+u), else bwd.
// ---------------------------------------------------------------------------
__global__ __launch_bounds__(256) void k_prep_wcp(const float* __restrict__ Wih_f,
                                                  const float* __restrict__ Wih_b,
                                                  short* __restrict__ WcatP)
{
    int idx = blockIdx.x * 256 + threadIdx.x;   // < 2*2432*320
    if (idx >= 2 * NPAD * 320) return;
    int p = idx / (NPAD * 320);
    int rem = idx - p * (NPAD * 320);
    int n = rem / 320;
    int kp = rem - n * 320;
    int fwd = (n < 1216);
    int nn = fwd ? n : n - 1216;
    float v = 0.f;
    if (kp < 300 && nn < G4_) {
        int u = nn >> 2, g = nn & 3;
        const float* W = fwd ? Wih_f : Wih_b;
        v = W[(size_t)(g * 300 + u) * K2E_ + (p ? 300 + kp : kp)];
    }
    WcatP[idx] = f2bf(v);
}

// ---------------------------------------------------------------------------
// Whh B-fragment pack: WF[d][(nt*10+kt)*512 + lane*8 + j] =
//   bf16(Whh_d[(g*300+u)*300 + k]),  n = nt*16+(lane&15) = 4u+g,
//   k = kt*32 + (lane>>4)*8 + j; zero pads.
// ---------------------------------------------------------------------------
__global__ __launch_bounds__(256) void k_prep_whh(const float* __restrict__ Whh_f,
                                                  const float* __restrict__ Whh_b,
                                                  short* __restrict__ WFf,
                                                  short* __restrict__ WFb)
{
    int idx = blockIdx.x * 256 + threadIdx.x;   // < 389120
    if (idx >= 389120) return;
    int d = blockIdx.y;
    int chunk = idx >> 9;           // nt*10+kt
    int rem   = idx & 511;
    int lane  = rem >> 3;
    int j     = rem & 7;
    int nt = chunk / 10, kt = chunk - nt * 10;
    int n = nt * 16 + (lane & 15);
    int k = kt * 32 + (lane >> 4) * 8 + j;
    float v = 0.f;
    if (n < G4_ && k < H_) {
        int u = n >> 2, g = n & 3;
        const float* W = d ? Whh_b : Whh_f;
        v = W[(size_t)(g * 300 + u) * H_ + k];
    }
    (d ? WFb : WFf)[idx] = f2bf(v);
}

// ---------------------------------------------------------------------------
// Wa B-fragment pack for k_out: N=304 (19 nt), K=608 (19 kt).
// ---------------------------------------------------------------------------
__global__ __launch_bounds__(256) void k_prep_wa(const float* __restrict__ Wa,
                                                 short* __restrict__ WAT)
{
    int idx = blockIdx.x * 256 + threadIdx.x;   // < 184832
    if (idx >= 184832) return;
    int chunk = idx >> 9;           // nt*19+kt
    int rem   = idx & 511;
    int lane  = rem >> 3;
    int j     = rem & 7;
    int nt = chunk / 19, kt = chunk - nt * 19;
    int o  = nt * 16 + (lane & 15);
    int kp = kt * 32 + (lane >> 4) * 8 + j;
    float v = 0.f;
    if (o < H_) {
        int k = -1;
        if (kp < 300)                   k = kp;
        else if (kp >= 304 && kp < 604) k = kp - 4;
        if (k >= 0) v = Wa[(size_t)o * K2E_ + k];
    }
    WAT[idx] = f2bf(v);
}

// ---------------------------------------------------------------------------
// a_g[b][e] = mean_l sem_table[sememes[b][l]][e]
// ---------------------------------------------------------------------------
__global__ __launch_bounds__(256) void k_ag(const int* __restrict__ sem,
                                            const float* __restrict__ sem_table,
                                            float* __restrict__ ag)
{
    int b = blockIdx.x;
    __shared__ int sm[L_];
    if (threadIdx.x < L_) sm[threadIdx.x] = sem[b * L_ + threadIdx.x];
    __syncthreads();
    for (int e = threadIdx.x; e < E_; e += 256) {
        float s = 0.f;
        #pragma unroll
        for (int l = 0; l < L_; ++l) s += sem_table[sm[l] * E_ + e];
        ag[(size_t)b * E_ + e] = s * (1.0f / (float)L_);
    }
}

// ---------------------------------------------------------------------------
// v_g = relu(a_g @ Wb^T + bb) -> d_out[VOFF + ...]
// ---------------------------------------------------------------------------
__global__ __launch_bounds__(256) void k_vg(const float* __restrict__ ag,
                                            const float* __restrict__ WbT,
                                            const float* __restrict__ bbv,
                                            float* __restrict__ out)
{
    int b0 = blockIdx.x * 16;
    __shared__ __align__(16) float ag_s[16 * E_];
    for (int idx = threadIdx.x; idx < 16 * E_; idx += 256)
        ag_s[idx] = ag[(size_t)b0 * E_ + idx];
    __syncthreads();
    for (int o = threadIdx.x; o < E_; o += 256) {
        float acc[16];
        #pragma unroll
        for (int i = 0; i < 16; ++i) acc[i] = 0.f;
        for (int k = 0; k < E_; ++k) {
            float w = WbT[k * E_ + o];
            #pragma unroll
            for (int i = 0; i < 16; ++i)
                acc[i] = fmaf(w, ag_s[i * E_ + k], acc[i]);
        }
        float bias = bbv[o];
        #pragma unroll
        for (int i = 0; i < 16; ++i) {
            float v = acc[i] + bias;
            out[VOFF + (size_t)(b0 + i) * E_ + o] = v > 0.f ? v : 0.f;
        }
    }
}

// ---------------------------------------------------------------------------
// k_p: P1 = w @ Wih1^T  (rows 0..1023, mb 0..7)
//      P2' = sem_table @ Wih2^T + bias  (rows 0..2303, mb 8..25)
// bf16 MFMA, 128x128 tiles, K=320 (300 valid). Grid (26, 19).
// ---------------------------------------------------------------------------
#define LDT 40

__global__ __launch_bounds__(256) void k_p(const int* __restrict__ word,
                                           const float* __restrict__ word_table,
                                           const float* __restrict__ sem_table,
                                           const short* __restrict__ WcatP,
                                           const float* __restrict__ bih_f,
                                           const float* __restrict__ bhh_f,
                                           const float* __restrict__ bih_b,
                                           const float* __restrict__ bhh_b,
                                           float* __restrict__ P1,
                                           float* __restrict__ P2)
{
    __shared__ __align__(16) short As[128 * LDT];
    __shared__ __align__(16) short Bs[128 * LDT];
    __shared__ const float* rowp[128];

    const int mb = blockIdx.x;
    const int p  = (mb >= 8);
    const int m0 = (p ? mb - 8 : mb) * 128;
    const int n0 = blockIdx.y * 128;
    const int tid = threadIdx.x;

    if (tid < 128) {
        int m = m0 + tid;
        rowp[tid] = p ? (m < 2186 ? sem_table + (size_t)m * E_ : (const float*)0)
                      : word_table + (size_t)word[m] * E_;
    }
    __syncthreads();

    f32x4 acc[4][4];
    #pragma unroll
    for (int i = 0; i < 4; ++i)
        #pragma unroll
        for (int j = 0; j < 4; ++j)
            acc[i][j] = (f32x4){0.f, 0.f, 0.f, 0.f};

    const int wv   = tid >> 6;
    const int lane = tid & 63;
    const int wm   = (wv >> 1) * 64;
    const int wn   = (wv & 1) * 64;
    const int lm   = lane & 15;
    const int quad = lane >> 4;

    const int r  = tid >> 1;
    const int kh = (tid & 1) * 16;
    const float* rp = rowp[r];
    const short* bsrc = WcatP + (size_t)p * (NPAD * 320) + (size_t)(n0 + r) * 320;

    for (int k0 = 0; k0 < 320; k0 += 32) {
        {
            const int kbase = k0 + kh;
            #pragma unroll
            for (int q = 0; q < 4; ++q) {
                int k = kbase + q * 4;
                float4 v = (k < E_ && rp) ? *(const float4*)&rp[k]
                                          : make_float4(0.f, 0.f, 0.f, 0.f);
                short4 s4;
                s4.x = f2bf(v.x); s4.y = f2bf(v.y);
                s4.z = f2bf(v.z); s4.w = f2bf(v.w);
                *(short4*)&As[r * LDT + kh + q * 4] = s4;
            }
        }
        {
            const short* src = bsrc + k0 + kh;
            *(int4*)&Bs[r * LDT + kh + 0] = *(const int4*)&src[0];
            *(int4*)&Bs[r * LDT + kh + 8] = *(const int4*)&src[8];
        }
        __syncthreads();

        bf16x8 af[4], bfr[4];
        #pragma unroll
        for (int i = 0; i < 4; ++i)
            af[i] = *(const bf16x8*)&As[(wm + 16 * i + lm) * LDT + quad * 8];
        #pragma unroll
        for (int j = 0; j < 4; ++j)
            bfr[j] = *(const bf16x8*)&Bs[(wn + 16 * j + lm) * LDT + quad * 8];
        #pragma unroll
        for (int i = 0; i < 4; ++i)
            #pragma unroll
            for (int j = 0; j < 4; ++j)
                acc[i][j] = __builtin_amdgcn_mfma_f32_16x16x32_bf16(
                    af[i], bfr[j], acc[i][j], 0, 0, 0);
        __syncthreads();
    }

    float* dst = p ? P2 : P1;
    #pragma unroll
    for (int j = 0; j < 4; ++j) {
        int n = n0 + wn + 16 * j + lm;
        float bias = 0.f;
        if (p) {
            int fwd = (n < 1216);
            int cc = fwd ? n : n - 1216;
            if (cc < G4_) {
                int u = cc >> 2, g = cc & 3;
                bias = fwd ? (bih_f[g * 300 + u] + bhh_f[g * 300 + u])
                           : (bih_b[g * 300 + u] + bhh_b[g * 300 + u]);
            }
        }
        #pragma unroll
        for (int i = 0; i < 4; ++i) {
            int mb2 = m0 + wm + 16 * i + quad * 4;
            #pragma unroll
            for (int reg = 0; reg < 4; ++reg)
                dst[(size_t)(mb2 + reg) * PSTR + n] = acc[i][j][reg] + bias;
        }
    }
}

// ---------------------------------------------------------------------------
// k_rec2: ALL 18 recurrence steps, persistent cooperative kernel.
// Grid (8 mb, 19 nb, 2 d) = 304 blocks x 256 thr; co-residency needs only
// 2 blocks/CU (512 >= 304) under __launch_bounds__(256,2).
// Whh B-frags resident in VGPRs; c-state in registers; grid.sync per step.
// ---------------------------------------------------------------------------
__global__ __launch_bounds__(256, 2) void k_rec2(const float* __restrict__ P1,
                                                 const float* __restrict__ P2,
                                                 const int* __restrict__ sem,
                                                 const short* __restrict__ WFf,
                                                 const short* __restrict__ WFb,
                                                 short* __restrict__ hp,
                                                 short* __restrict__ hcat)
{
    cg::grid_group gg = cg::this_grid();

    const int d  = blockIdx.z;
    const short* WF = d ? WFb : WFf;
    short* hc = hcat + (d ? 304 : 0);
    const int rt0 = blockIdx.x * 8;       // 8 row-tiles = 128 batch rows
    const int nb  = blockIdx.y;           // units nb*16..+15
    const int tid  = threadIdx.x;
    const int lane = tid & 63;
    const int wv   = tid >> 6;
    const int quad = lane >> 4;

    __shared__ __align__(16) float Cs[128][68];   // 34.8 KB

    // resident Whh B-fragments for (nb, wv, d): 10 x bf16x8 = 40 VGPRs
    bf16x8 bfr[10];
    {
        const short* wp = WF + ((size_t)(nb * 4 + wv) * 10) * 512 + lane * 8;
        #pragma unroll
        for (int kt = 0; kt < 10; ++kt)
            bfr[kt] = *(const bf16x8*)(wp + kt * 512);
    }

    // epilogue thread roles: 128 rows x 2 unit-halves (8 units/thread)
    const int m  = tid >> 1;              // 0..127
    const int q  = tid & 1;
    const int b  = rt0 * 16 + m;
    const int u0 = nb * 16 + 8 * q;
    const bool a0 = (u0 < H_);
    const bool a1 = (u0 + 4 < H_);
    const size_t pcol = (size_t)d * 1216 + 4 * u0;
    const float* p1r = P1 + (size_t)b * PSTR + pcol;
    float c8[8] = {0.f,0.f,0.f,0.f,0.f,0.f,0.f,0.f};

    // hp fragment-layout offset (u0 and u0+4 chunks are hofs and hofs+4)
    size_t hofs;
    {
        int rt = b >> 4, ktu = u0 >> 5;
        int fl = (b & 15) | (((u0 >> 3) & 3) << 4);
        hofs = ((size_t)(rt * 10 + ktu) * 512) + (size_t)fl * 8 + (u0 & 7);
    }

    for (int s = 0; s < L_; ++s) {
        const int t = d ? (L_ - 1 - s) : s;
        const short* hin = hp + (size_t)(d * 2 + ((s + 1) & 1)) * HPSTR;
        short*      hout = hp + (size_t)(d * 2 + (s & 1)) * HPSTR;

        // ---- gather x-part early (independent of recurrence GEMM) ----
        float4 xv[8];
        {
            const int svt = sem[b * L_ + t];
            const float* p2r = P2 + (size_t)svt * PSTR + pcol;
            #pragma unroll
            for (int i = 0; i < 8; ++i) xv[i] = *(const float4*)&p2r[4 * i];
            if (svt != 0) {
                #pragma unroll
                for (int i = 0; i < 8; ++i) {
                    float4 a = *(const float4*)&p1r[4 * i];
                    xv[i].x += a.x; xv[i].y += a.y; xv[i].z += a.z; xv[i].w += a.w;
                }
            }
        }

        // ---- gates = h_prev @ Whh^T (MFMA) ----
        f32x4 acc[8];
        #pragma unroll
        for (int mt = 0; mt < 8; ++mt) acc[mt] = (f32x4){0.f, 0.f, 0.f, 0.f};
        if (s > 0) {
            #pragma unroll
            for (int kt = 0; kt < 10; ++kt) {
                #pragma unroll
                for (int mt = 0; mt < 8; ++mt) {
                    bf16x8 af = *(const bf16x8*)&hin[((size_t)(rt0 + mt) * 10 + kt) * 512 + lane * 8];
                    acc[mt] = __builtin_amdgcn_mfma_f32_16x16x32_bf16(af, bfr[kt], acc[mt], 0, 0, 0);
                }
            }
        }

        // ---- C tile -> LDS (wave wv owns cols wv*16..+15) ----
        #pragma unroll
        for (int mt = 0; mt < 8; ++mt)
            #pragma unroll
            for (int r = 0; r < 4; ++r)
                Cs[mt * 16 + quad * 4 + r][wv * 16 + (lane & 15)] = acc[mt][r];
        __syncthreads();

        // ---- fused LSTM cell (8 units/thread) ----
        {
            short hn[8];
            #pragma unroll
            for (int i = 0; i < 8; ++i) {
                float4 gv = *(const float4*)&Cs[m][32 * q + 4 * i];
                float gi = xv[i].x + gv.x;
                float gf = xv[i].y + gv.y;
                float gg2 = xv[i].z + gv.z;
                float go = xv[i].w + gv.w;
                float iv = 1.f / (1.f + __expf(-gi));
                float fv = 1.f / (1.f + __expf(-gf));
                float tg = 1.f - 2.f / (__expf(2.f * gg2) + 1.f);
                float ov = 1.f / (1.f + __expf(-go));
                float cc = fmaf(fv, c8[i], iv * tg);
                c8[i] = cc;
                float th = 1.f - 2.f / (__expf(2.f * cc) + 1.f);
                hn[i] = f2bf(ov * th);
            }
            if (a0) {
                short4 h4 = {hn[0], hn[1], hn[2], hn[3]};
                *(short4*)&hout[hofs] = h4;
                *(short4*)&hc[((size_t)b * L_ + t) * 608 + u0] = h4;
            }
            if (a1) {
                short4 h4 = {hn[4], hn[5], hn[6], hn[7]};
                *(short4*)&hout[hofs + 4] = h4;
                *(short4*)&hc[((size_t)b * L_ + t) * 608 + u0 + 4] = h4;
            }
        }

        __threadfence();   // device-scope release of hout/hcat before grid sync
        gg.sync();         // also serves as the intra-block barrier for Cs reuse
    }
}

// ---------------------------------------------------------------------------
// k_step2 (fallback path): ONE recurrence step, both dirs.
// Grid (16 mb, 19 nb, 2 d), 256 thr. Identical arithmetic to k_rec2.
// ---------------------------------------------------------------------------
__global__ __launch_bounds__(256) void k_step2(const float* __restrict__ P1,
                                               const float* __restrict__ P2,
                                               const int* __restrict__ sem,
                                               const short* __restrict__ WFf,
                                               const short* __restrict__ WFb,
                                               short* __restrict__ hp,
                                               float* __restrict__ cbuf,
                                               short* __restrict__ hcat,
                                               int s)
{
    const int d  = blockIdx.z;
    const short* WF = d ? WFb : WFf;
    const int t = d ? (L_ - 1 - s) : s;
    const short* hin = hp + (size_t)(d * 2 + ((s + 1) & 1)) * HPSTR;
    short*      hout = hp + (size_t)(d * 2 + (s & 1)) * HPSTR;
    short* hc = hcat + (d ? 304 : 0);
    float* cp = cbuf + (size_t)d * (1024 * 304);

    const int m0 = blockIdx.x * 64;
    const int rt0 = blockIdx.x * 4;
    const int nb = blockIdx.y;
    const int tid  = threadIdx.x;
    const int lane = tid & 63;
    const int wv   = tid >> 6;
    const int quad = lane >> 4;

    __shared__ __align__(16) float Cs[64][68];

    f32x4 acc[4];
    #pragma unroll
    for (int mt = 0; mt < 4; ++mt) acc[mt] = (f32x4){0.f, 0.f, 0.f, 0.f};

    if (s > 0) {
        const short* wp = WF + ((size_t)(nb * 4 + wv) * 10) * 512 + lane * 8;
        #pragma unroll
        for (int kt = 0; kt < 10; ++kt) {
            bf16x8 bf = *(const bf16x8*)(wp + kt * 512);
            #pragma unroll
            for (int mt = 0; mt < 4; ++mt) {
                bf16x8 af = *(const bf16x8*)&hin[((size_t)(rt0 + mt) * 10 + kt) * 512 + lane * 8];
                acc[mt] = __builtin_amdgcn_mfma_f32_16x16x32_bf16(af, bf, acc[mt], 0, 0, 0);
            }
        }
    }

    #pragma unroll
    for (int mt = 0; mt < 4; ++mt)
        #pragma unroll
        for (int r = 0; r < 4; ++r)
            Cs[mt * 16 + quad * 4 + r][wv * 16 + (lane & 15)] = acc[mt][r];
    __syncthreads();

    const int m = tid >> 2;
    const int q = tid & 3;
    const int b = m0 + m;
    const int u0 = nb * 16 + 4 * q;
    if (u0 < H_) {
        const int svt = sem[b * L_ + t];
        const size_t pcol = (size_t)d * 1216 + 4 * u0;
        const float* p2r = P2 + (size_t)svt * PSTR + pcol;
        const float* p1r = P1 + (size_t)b * PSTR + pcol;
        float4 xv[4];
        #pragma unroll
        for (int i = 0; i < 4; ++i) xv[i] = *(const float4*)&p2r[4 * i];
        if (svt != 0) {
            #pragma unroll
            for (int i = 0; i < 4; ++i) {
                float4 a = *(const float4*)&p1r[4 * i];
                xv[i].x += a.x; xv[i].y += a.y; xv[i].z += a.z; xv[i].w += a.w;
            }
        }
        float4 cpv = (s > 0) ? *(const float4*)&cp[(size_t)b * 304 + u0]
                             : make_float4(0.f, 0.f, 0.f, 0.f);
        float cold[4] = {cpv.x, cpv.y, cpv.z, cpv.w};
        float cnew[4];
        short hn[4];
        #pragma unroll
        for (int i = 0; i < 4; ++i) {
            float4 gv = *(const float4*)&Cs[m][16 * q + 4 * i];
            float gi = xv[i].x + gv.x;
            float gf = xv[i].y + gv.y;
            float gg = xv[i].z + gv.z;
            float go = xv[i].w + gv.w;
            float iv = 1.f / (1.f + __expf(-gi));
            float fv = 1.f / (1.f + __expf(-gf));
            float tg = 1.f - 2.f / (__expf(2.f * gg) + 1.f);
            float ov = 1.f / (1.f + __expf(-go));
            float cc = fmaf(fv, cold[i], iv * tg);
            cnew[i] = cc;
            float th = 1.f - 2.f / (__expf(2.f * cc) + 1.f);
            hn[i] = f2bf(ov * th);
        }
        *(float4*)&cp[(size_t)b * 304 + u0] = make_float4(cnew[0], cnew[1], cnew[2], cnew[3]);
        short4 h4 = {hn[0], hn[1], hn[2], hn[3]};
        {
            int rt = b >> 4, ktu = u0 >> 5;
            int fl = (b & 15) | (((u0 >> 3) & 3) << 4);
            *(short4*)&hout[((size_t)(rt * 10 + ktu) * 512) + (size_t)fl * 8 + (u0 & 7)] = h4;
        }
        *(short4*)&hc[((size_t)b * L_ + t) * 608 + u0] = h4;
    }
}

// ---------------------------------------------------------------------------
// k_out: V = relu(hcat @ WAT^T + ba)  bf16 MFMA.  M=18432, N=304(300), K=608.
// ---------------------------------------------------------------------------
__global__ __launch_bounds__(256) void k_out(const short* __restrict__ hcat,
                                             const short* __restrict__ WAT,
                                             const float* __restrict__ ba,
                                             float* __restrict__ out)
{
    const int m0 = blockIdx.x * 64;
    const int tid = threadIdx.x;
    const int lane = tid & 63;
    const int wv = tid >> 6;
    const int lm = lane & 15;
    const int quad = lane >> 4;

    __shared__ __align__(16) short A_s[64][616];

    for (int idx = tid; idx < 4864; idx += 256) {   // 64 rows * 76 chunks
        int r = idx / 76, c8 = idx - r * 76;
        *(int4*)&A_s[r][c8 * 8] = *(const int4*)&hcat[(size_t)(m0 + r) * 608 + c8 * 8];
    }
    __syncthreads();

    f32x4 acc[4][5];
    #pragma unroll
    for (int mt = 0; mt < 4; ++mt)
        #pragma unroll
        for (int q = 0; q < 5; ++q)
            acc[mt][q] = (f32x4){0.f, 0.f, 0.f, 0.f};

    for (int kt = 0; kt < 19; ++kt) {
        bf16x8 af[4];
        #pragma unroll
        for (int mt = 0; mt < 4; ++mt)
            af[mt] = *(const bf16x8*)&A_s[mt * 16 + lm][kt * 32 + quad * 8];
        #pragma unroll
        for (int q = 0; q < 5; ++q) {
            int nt = wv + 4 * q;
            if (nt < 19) {
                bf16x8 bf = *(const bf16x8*)&WAT[((size_t)(nt * 19 + kt) * 64 + lane) * 8];
                #pragma unroll
                for (int mt = 0; mt < 4; ++mt)
                    acc[mt][q] = __builtin_amdgcn_mfma_f32_16x16x32_bf16(
                        af[mt], bf, acc[mt][q], 0, 0, 0);
            }
        }
    }

    #pragma unroll
    for (int q = 0; q < 5; ++q) {
        int nt = wv + 4 * q;
        if (nt < 19) {
            int o = nt * 16 + lm;
            if (o < H_) {
                float bias = ba[o];
                #pragma unroll
                for (int mt = 0; mt < 4; ++mt) {
                    #pragma unroll
                    for (int r = 0; r < 4; ++r) {
                        int m = m0 + mt * 16 + quad * 4 + r;
                        float v = acc[mt][q][r] + bias;
                        out[(size_t)m * H_ + o] = v > 0.f ? v : 0.f;
                    }
                }
            }
        }
    }
}

// ---------------------------------------------------------------------------
extern "C" void kernel_launch(void* const* d_in, const int* in_sizes, int n_in,
                              void* d_out, int out_size, void* d_ws, size_t ws_size,
                              hipStream_t stream) {
    const int*   word       = (const int*)  d_in[0];
    const int*   sem        = (const int*)  d_in[1];
    const float* word_table = (const float*)d_in[2];
    const float* sem_table  = (const float*)d_in[3];
    const float* Wih_f      = (const float*)d_in[4];
    const float* Whh_f      = (const float*)d_in[5];
    const float* bih_f      = (const float*)d_in[6];
    const float* bhh_f      = (const float*)d_in[7];
    const float* Wih_b      = (const float*)d_in[8];
    const float* Whh_b      = (const float*)d_in[9];
    const float* bih_b      = (const float*)d_in[10];
    const float* bhh_b      = (const float*)d_in[11];
    const float* Wa         = (const float*)d_in[12];
    const float* ba         = (const float*)d_in[13];
    const float* Wb         = (const float*)d_in[14];
    const float* bbv        = (const float*)d_in[15];

    float* out = (float*)d_out;
    float* ws  = (float*)d_ws;

    float* P1    = ws + OFF_P1;
    float* P2    = ws + OFF_P2;
    short* hcat  = (short*)(ws + OFF_HCAT);
    float* ag    = ws + OFF_AG;
    float* WbT   = ws + OFF_WBT;
    short* WFf   = (short*)(ws + OFF_WFF);
    short* WFb   = (short*)(ws + OFF_WFB);
    short* WAT   = (short*)(ws + OFF_WAT);
    short* WcatP = (short*)(ws + OFF_WCP);
    short* hp    = (short*)(ws + OFF_HP);
    float* cbuf  = ws + OFF_C;

    // weight re-layouts (every call; inputs restored each launch)
    k_prep<<<dim3(352), dim3(256), 0, stream>>>(Wb, WbT);
    k_prep_wcp<<<dim3((2 * NPAD * 320 + 255) / 256), dim3(256), 0, stream>>>(
        Wih_f, Wih_b, WcatP);
    k_prep_whh<<<dim3(1520, 2), dim3(256), 0, stream>>>(Whh_f, Whh_b, WFf, WFb);
    k_prep_wa<<<dim3(722), dim3(256), 0, stream>>>(Wa, WAT);

    // v_g branch
    k_ag<<<dim3(B_), dim3(256), 0, stream>>>(sem, sem_table, ag);
    k_vg<<<dim3(B_ / 16), dim3(256), 0, stream>>>(ag, WbT, bbv, out);

    // factored input GEMMs: P1 (word part) + P2' (sememe part + bias)
    k_p<<<dim3(26, 19), dim3(256), 0, stream>>>(
        word, word_table, sem_table, WcatP,
        bih_f, bhh_f, bih_b, bhh_b, P1, P2);

    // recurrence: cooperative single-launch if the runtime guarantees
    // co-residency of 304 blocks; otherwise proven 18-launch fallback.
    // All gating inputs are pure host queries -> same decision every call.
    int useCoop = 0;
    {
        int dev = 0, coopAttr = 0, numCU = 0, maxBlk = 0;
        (void)hipGetDevice(&dev);
        (void)hipDeviceGetAttribute(&coopAttr, hipDeviceAttributeCooperativeLaunch, dev);
        (void)hipDeviceGetAttribute(&numCU, hipDeviceAttributeMultiprocessorCount, dev);
        (void)hipOccupancyMaxActiveBlocksPerMultiprocessor(&maxBlk, k_rec2, 256, 0);
        if (coopAttr && (long)maxBlk * (long)numCU >= 304) useCoop = 1;
    }
    if (useCoop) {
        void* args[] = {(void*)&P1, (void*)&P2, (void*)&sem,
                        (void*)&WFf, (void*)&WFb, (void*)&hp, (void*)&hcat};
        hipError_t e = hipLaunchCooperativeKernel((const void*)k_rec2,
                                                  dim3(8, 19, 2), dim3(256),
                                                  args, 0, stream);
        if (e != hipSuccess) useCoop = 0;
    }
    if (!useCoop) {
        for (int s = 0; s < L_; ++s) {
            k_step2<<<dim3(16, 19, 2), dim3(256), 0, stream>>>(
                P1, P2, sem, WFf, WFb, hp, cbuf, hcat, s);
        }
    }

    // output projection (bf16 MFMA)
    k_out<<<dim3(M_ / 64), dim3(256), 0, stream>>>(hcat, WAT, ba, out);
}